// Round 2
// baseline (172.291 us; speedup 1.0000x reference)
//
#include <hip/hip_runtime.h>
#include <stdint.h>

typedef __attribute__((ext_vector_type(8))) _Float16 f16x8;
typedef __attribute__((ext_vector_type(4))) float f32x4;
typedef __attribute__((ext_vector_type(2))) unsigned int u32x2;

#define S_ 4096
#define D_ 1024

// ---------------------------------------------------------------------------
// Projections. qk[s][256] (f16) = [x@Wq^T | x@Wk^T]; vt[b][f][s] (f16) = V^T.
// 128x128 tile, BK=32, 4 waves (2x2). fp32 x/W staged via global_load_lds
// (width 16) with source-side granule XOR swizzle (^row&7) so fragment
// ds_read_b128s don't hit the 16-way row-aligned bank conflict.
// by = 0:Q, 1:K (direct store), 2:V (transposed store via LDS).
// ---------------------------------------------------------------------------
__global__ __launch_bounds__(256) void gemm_qkv(
    const float* __restrict__ x, const float* __restrict__ Wq,
    const float* __restrict__ Wk, const float* __restrict__ Wv,
    _Float16* __restrict__ qk, _Float16* __restrict__ vt)
{
  __shared__ char smem[32768];
  float* At = (float*)smem;             // [128][32] f32
  float* Bt = (float*)(smem + 16384);   // [128][32] f32
  const int tid  = threadIdx.x;
  const int lane = tid & 63, wid = tid >> 6;
  const int g = lane >> 4, l15 = lane & 15;
  const int wr = wid >> 1, wc = wid & 1;
  const int m0 = blockIdx.x * 128;
  const int by = blockIdx.y;
  const float* W = (by == 0) ? Wq : ((by == 1) ? Wk : Wv);

  f32x4 acc[4][4] = {};

  for (int k0 = 0; k0 < D_; k0 += 32) {
    #pragma unroll
    for (int it = 0; it < 4; ++it) {
      int G   = it * 256 + tid;          // 16B granule, 0..1023
      int row = G >> 3;                  // 8 granules per 32-float row
      int cb  = ((G & 7) ^ (row & 7)) << 4;
      const char* ga = (const char*)x + (size_t)(m0 + row) * 4096 + k0 * 4 + cb;
      const char* gb = (const char*)W + (size_t)row * 4096 + k0 * 4 + cb;
      __builtin_amdgcn_global_load_lds(ga, (char*)At + (it * 256 + wid * 64) * 16, 16, 0, 0);
      __builtin_amdgcn_global_load_lds(gb, (char*)Bt + (it * 256 + wid * 64) * 16, 16, 0, 0);
    }
    __syncthreads();

    f16x8 af[4], bg[4];
    #pragma unroll
    for (int mt = 0; mt < 4; ++mt) {
      int row = wr * 64 + mt * 16 + l15;
      const char* base = (const char*)At + row * 128;
      f32x4 a0 = *(const f32x4*)(base + (((2 * g    ) ^ (row & 7)) << 4));
      f32x4 a1 = *(const f32x4*)(base + (((2 * g + 1) ^ (row & 7)) << 4));
      #pragma unroll
      for (int i = 0; i < 4; ++i) { af[mt][i] = (_Float16)a0[i]; af[mt][i + 4] = (_Float16)a1[i]; }
    }
    #pragma unroll
    for (int nt = 0; nt < 4; ++nt) {
      int row = wc * 64 + nt * 16 + l15;
      const char* base = (const char*)Bt + row * 128;
      f32x4 b0 = *(const f32x4*)(base + (((2 * g    ) ^ (row & 7)) << 4));
      f32x4 b1 = *(const f32x4*)(base + (((2 * g + 1) ^ (row & 7)) << 4));
      #pragma unroll
      for (int i = 0; i < 4; ++i) { bg[nt][i] = (_Float16)b0[i]; bg[nt][i + 4] = (_Float16)b1[i]; }
    }

    #pragma unroll
    for (int mt = 0; mt < 4; ++mt)
      #pragma unroll
      for (int nt = 0; nt < 4; ++nt)
        acc[mt][nt] = __builtin_amdgcn_mfma_f32_16x16x32_f16(af[mt], bg[nt], acc[mt][nt], 0, 0, 0);
    __syncthreads();
  }

  if (by < 2) {
    // D layout (m89): col = lane&15, row = 4*(lane>>4)+reg
    #pragma unroll
    for (int mt = 0; mt < 4; ++mt)
      #pragma unroll
      for (int nt = 0; nt < 4; ++nt)
        #pragma unroll
        for (int r = 0; r < 4; ++r) {
          int row = m0 + wr * 64 + mt * 16 + (g << 2) + r;
          int col = by * 128 + wc * 64 + nt * 16 + l15;
          qk[(size_t)row * 256 + col] = (_Float16)acc[mt][nt][r];
        }
  } else {
    // V: transpose 128(s) x 128(f) tile through LDS, store vt[b][f][s] coalesced
    _Float16* T = (_Float16*)smem;      // [128 s][128 f], overlays At/Bt (post-barrier)
    #pragma unroll
    for (int mt = 0; mt < 4; ++mt)
      #pragma unroll
      for (int nt = 0; nt < 4; ++nt)
        #pragma unroll
        for (int r = 0; r < 4; ++r)
          T[(wr * 64 + mt * 16 + (g << 2) + r) * 128 + wc * 64 + nt * 16 + l15] =
              (_Float16)acc[mt][nt][r];
    __syncthreads();
    const int b = m0 >> 12, s_base = m0 & 4095;
    #pragma unroll
    for (int it = 0; it < 8; ++it) {
      int Wn = it * 256 + tid;           // 0..2047
      int f = Wn >> 4, c8 = Wn & 15;
      f16x8 v;
      #pragma unroll
      for (int j = 0; j < 8; ++j) v[j] = T[(c8 * 8 + j) * 128 + f];
      *(f16x8*)(vt + (size_t)(b * 128 + f) * 4096 + s_base + c8 * 8) = v;
    }
  }
}

// ---------------------------------------------------------------------------
// Flash attention. Block: 64 q-rows (4 waves x 16), 64 KV tiles of 64.
// Swapped QK^T: sacc = mfma(K, Q) -> lane(g,l15) holds S[q=l15][kv=16kvt+4g+r];
// wave-parallel softmax (shfl_xor 16,32 over g); P stays in registers with
// natural slot map kv = 32kk + 4g + 16*(i>>2) + (i&3). V comes PRE-TRANSPOSED
// (vt[f][s]) so the matching B-fragment is two plain u32x2 LDS reads per
// fragment from Vl[f][kv] (XOR-swizzled rows). No inline asm anywhere.
// ---------------------------------------------------------------------------
__global__ __launch_bounds__(256) void attn(const _Float16* __restrict__ qk,
                                            const _Float16* __restrict__ vt,
                                            float* __restrict__ out)
{
  __shared__ _Float16 Kl[64 * 128];     // [kv][d], rows XOR-swizzled (^row&15 granules)
  __shared__ _Float16 Vl[128 * 64];     // [f][kv], rows XOR-swizzled (^row&7 granules)
  const int tid  = threadIdx.x;
  const int lane = tid & 63, wid = tid >> 6;
  const int g = lane >> 4, l15 = lane & 15;
  const int b  = blockIdx.y;
  const int q0 = blockIdx.x * 64;

  f16x8 qf[4];
  {
    const size_t qrow = (size_t)(b * S_ + q0 + wid * 16 + l15) * 256;
    #pragma unroll
    for (int kk = 0; kk < 4; ++kk)
      qf[kk] = *(const f16x8*)(qk + qrow + kk * 32 + g * 8);
  }

  f32x4 oacc[8] = {};
  float m_run = -1e30f, l_run = 0.f;

  for (int t = 0; t < 64; ++t) {
    const int kv0 = t * 64;
    #pragma unroll
    for (int it = 0; it < 4; ++it) {     // K tile [64][128]
      int G   = it * 256 + tid;
      int row = G >> 4;
      int cb  = (((G & 15) << 4)) ^ ((row & 15) << 4);
      const char* ga = (const char*)qk + (size_t)(b * S_ + kv0 + row) * 512 + 256 + cb;
      __builtin_amdgcn_global_load_lds(ga, (char*)Kl + (it * 256 + wid * 64) * 16, 16, 0, 0);
    }
    #pragma unroll
    for (int it = 0; it < 4; ++it) {     // V^T tile [128][64]
      int G  = it * 256 + tid;
      int f  = G >> 3, pc = G & 7;
      const char* ga = (const char*)vt + ((size_t)(b * 128 + f) * 4096 + kv0) * 2 +
                       (((pc ^ (f & 7)) << 4));
      __builtin_amdgcn_global_load_lds(ga, (char*)Vl + (it * 256 + wid * 64) * 16, 16, 0, 0);
    }
    __syncthreads();

    f32x4 sacc[4] = {};
    #pragma unroll
    for (int kk = 0; kk < 4; ++kk)
      #pragma unroll
      for (int kvt = 0; kvt < 4; ++kvt) {
        int row = kvt * 16 + l15;
        f16x8 kf = *(const f16x8*)((const char*)Kl + row * 256 +
                                   ((kk * 64 + g * 16) ^ ((row & 15) << 4)));
        sacc[kvt] = __builtin_amdgcn_mfma_f32_16x16x32_f16(kf, qf[kk], sacc[kvt], 0, 0, 0);
      }

    float sv[4][4];
    float mloc = -1e30f;
    #pragma unroll
    for (int kvt = 0; kvt < 4; ++kvt)
      #pragma unroll
      for (int r = 0; r < 4; ++r) {
        float s = sacc[kvt][r] * 0.03125f;      // 1/sqrt(1024)
        sv[kvt][r] = s;
        mloc = fmaxf(mloc, s);
      }
    mloc = fmaxf(mloc, __shfl_xor(mloc, 16));
    mloc = fmaxf(mloc, __shfl_xor(mloc, 32));
    float m_new = fmaxf(m_run, mloc);
    float corr  = __expf(m_run - m_new);
    float psum  = 0.f;
    _Float16 pb[4][4];
    #pragma unroll
    for (int kvt = 0; kvt < 4; ++kvt)
      #pragma unroll
      for (int r = 0; r < 4; ++r) {
        float p = __expf(sv[kvt][r] - m_new);
        psum += p;
        pb[kvt][r] = (_Float16)p;
      }
    psum += __shfl_xor(psum, 16);
    psum += __shfl_xor(psum, 32);
    l_run = l_run * corr + psum;
    m_run = m_new;

    #pragma unroll
    for (int r = 0; r < 4; ++r) {          // O lives at q = 4g+r: pull corr[4g+r]
      float cr = __builtin_bit_cast(float,
                   __builtin_amdgcn_ds_bpermute((((g << 2) + r) << 2),
                                                __builtin_bit_cast(int, corr)));
      #pragma unroll
      for (int ft = 0; ft < 8; ++ft) oacc[ft][r] *= cr;
    }

    f16x8 pa[2];
    #pragma unroll
    for (int kk = 0; kk < 2; ++kk)
      #pragma unroll
      for (int i = 0; i < 8; ++i)
        pa[kk][i] = pb[2 * kk + (i >> 2)][i & 3];

    #pragma unroll
    for (int kk = 0; kk < 2; ++kk)
      #pragma unroll
      for (int ft = 0; ft < 8; ++ft) {
        int row = ft * 16 + l15;
        int swz = (row & 7) << 4;
        const char* rb = (const char*)Vl + row * 128;
        u32x2 w0 = *(const u32x2*)(rb + ((kk * 64 + g * 8     ) ^ swz));
        u32x2 w1 = *(const u32x2*)(rb + ((kk * 64 + g * 8 + 32) ^ swz));
        f16x8 vf;
        ((u32x2*)&vf)[0] = w0;
        ((u32x2*)&vf)[1] = w1;
        oacc[ft] = __builtin_amdgcn_mfma_f32_16x16x32_f16(pa[kk], vf, oacc[ft], 0, 0, 0);
      }
    __syncthreads();
  }

  #pragma unroll
  for (int r = 0; r < 4; ++r) {
    float lr = __builtin_bit_cast(float,
                 __builtin_amdgcn_ds_bpermute((((g << 2) + r) << 2),
                                              __builtin_bit_cast(int, l_run)));
    float inv = 1.f / lr;
    const size_t orow = (size_t)(b * S_ + q0 + wid * 16 + (g << 2) + r) * 128;
    #pragma unroll
    for (int ft = 0; ft < 8; ++ft)
      out[orow + ft * 16 + l15] = oacc[ft][r] * inv;
  }
}

extern "C" void kernel_launch(void* const* d_in, const int* in_sizes, int n_in,
                              void* d_out, int out_size, void* d_ws, size_t ws_size,
                              hipStream_t stream)
{
  (void)in_sizes; (void)n_in; (void)out_size; (void)ws_size;
  const float* x  = (const float*)d_in[0];
  const float* Wq = (const float*)d_in[1];
  const float* Wk = (const float*)d_in[2];
  const float* Wv = (const float*)d_in[3];
  _Float16* qkbuf = (_Float16*)d_ws;                              // 16384 x 256 f16 = 8.39 MB
  _Float16* vtbuf = (_Float16*)((char*)d_ws + (size_t)16384 * 256 * 2);  // 4 x 128 x 4096 f16 = 4 MB
  float* out = (float*)d_out;

  dim3 gg(128, 3);
  gemm_qkv<<<gg, 256, 0, stream>>>(x, Wq, Wk, Wv, qkbuf, vtbuf);
  dim3 ga(64, 4);
  attn<<<ga, 256, 0, stream>>>(qkbuf, vtbuf, out);
}

// Round 4
// 134.433 us; speedup vs baseline: 1.2816x; 1.2816x over previous
//
#include <hip/hip_runtime.h>
#include <stdint.h>

typedef __attribute__((ext_vector_type(8))) _Float16 f16x8;
typedef __attribute__((ext_vector_type(4))) float f32x4;
typedef __attribute__((ext_vector_type(2))) unsigned int u32x2;
typedef __attribute__((ext_vector_type(2))) float f32x2;

#define S_ 4096
#define D_ 1024
#define NROWS 16384          // B*S

// ---------------------------------------------------------------------------
// Projections. qk[s][256] (f16) = [x@Wq^T | x@Wk^T]; vt[b][f][s] (f16) = V^T.
// 128x128 tile, BK=32, 4 waves (2x2), fp32 staged via global_load_lds with
// source-side granule XOR swizzle so fragment ds_read_b128s are conflict-free.
// ---------------------------------------------------------------------------
__global__ __launch_bounds__(256) void gemm_qkv(
    const float* __restrict__ x, const float* __restrict__ Wq,
    const float* __restrict__ Wk, const float* __restrict__ Wv,
    _Float16* __restrict__ qk, _Float16* __restrict__ vt)
{
  __shared__ char smem[32768];
  float* At = (float*)smem;             // [128][32] f32
  float* Bt = (float*)(smem + 16384);   // [128][32] f32
  const int tid  = threadIdx.x;
  const int lane = tid & 63, wid = tid >> 6;
  const int g = lane >> 4, l15 = lane & 15;
  const int wr = wid >> 1, wc = wid & 1;
  const int m0 = blockIdx.x * 128;
  const int by = blockIdx.y;
  const float* W = (by == 0) ? Wq : ((by == 1) ? Wk : Wv);

  f32x4 acc[4][4] = {};

  for (int k0 = 0; k0 < D_; k0 += 32) {
    #pragma unroll
    for (int it = 0; it < 4; ++it) {
      int G   = it * 256 + tid;          // 16B granule, 0..1023
      int row = G >> 3;
      int cb  = ((G & 7) ^ (row & 7)) << 4;
      const char* ga = (const char*)x + (size_t)(m0 + row) * 4096 + k0 * 4 + cb;
      const char* gb = (const char*)W + (size_t)row * 4096 + k0 * 4 + cb;
      __builtin_amdgcn_global_load_lds(ga, (char*)At + (it * 256 + wid * 64) * 16, 16, 0, 0);
      __builtin_amdgcn_global_load_lds(gb, (char*)Bt + (it * 256 + wid * 64) * 16, 16, 0, 0);
    }
    __syncthreads();

    f16x8 af[4], bg[4];
    #pragma unroll
    for (int mt = 0; mt < 4; ++mt) {
      int row = wr * 64 + mt * 16 + l15;
      const char* base = (const char*)At + row * 128;
      f32x4 a0 = *(const f32x4*)(base + (((2 * g    ) ^ (row & 7)) << 4));
      f32x4 a1 = *(const f32x4*)(base + (((2 * g + 1) ^ (row & 7)) << 4));
      #pragma unroll
      for (int i = 0; i < 4; ++i) { af[mt][i] = (_Float16)a0[i]; af[mt][i + 4] = (_Float16)a1[i]; }
    }
    #pragma unroll
    for (int nt = 0; nt < 4; ++nt) {
      int row = wc * 64 + nt * 16 + l15;
      const char* base = (const char*)Bt + row * 128;
      f32x4 b0 = *(const f32x4*)(base + (((2 * g    ) ^ (row & 7)) << 4));
      f32x4 b1 = *(const f32x4*)(base + (((2 * g + 1) ^ (row & 7)) << 4));
      #pragma unroll
      for (int i = 0; i < 4; ++i) { bg[nt][i] = (_Float16)b0[i]; bg[nt][i + 4] = (_Float16)b1[i]; }
    }

    __builtin_amdgcn_s_setprio(1);
    #pragma unroll
    for (int mt = 0; mt < 4; ++mt)
      #pragma unroll
      for (int nt = 0; nt < 4; ++nt)
        acc[mt][nt] = __builtin_amdgcn_mfma_f32_16x16x32_f16(af[mt], bg[nt], acc[mt][nt], 0, 0, 0);
    __builtin_amdgcn_s_setprio(0);
    __syncthreads();
  }

  if (by < 2) {
    // D layout (m89): col = lane&15, row = 4*(lane>>4)+reg
    #pragma unroll
    for (int mt = 0; mt < 4; ++mt)
      #pragma unroll
      for (int nt = 0; nt < 4; ++nt)
        #pragma unroll
        for (int r = 0; r < 4; ++r) {
          int row = m0 + wr * 64 + mt * 16 + (g << 2) + r;
          int col = by * 128 + wc * 64 + nt * 16 + l15;
          qk[(size_t)row * 256 + col] = (_Float16)acc[mt][nt][r];
        }
  } else {
    // V: transpose 128(s) x 128(f) tile through LDS, store vt[b][f][s] coalesced
    _Float16* T = (_Float16*)smem;
    #pragma unroll
    for (int mt = 0; mt < 4; ++mt)
      #pragma unroll
      for (int nt = 0; nt < 4; ++nt)
        #pragma unroll
        for (int r = 0; r < 4; ++r)
          T[(wr * 64 + mt * 16 + (g << 2) + r) * 128 + wc * 64 + nt * 16 + l15] =
              (_Float16)acc[mt][nt][r];
    __syncthreads();
    const int b = m0 >> 12, s_base = m0 & 4095;
    #pragma unroll
    for (int it = 0; it < 8; ++it) {
      int Wn = it * 256 + tid;
      int f = Wn >> 4, c8 = Wn & 15;
      f16x8 v;
      #pragma unroll
      for (int j = 0; j < 8; ++j) v[j] = T[(c8 * 8 + j) * 128 + f];
      *(f16x8*)(vt + (size_t)(b * 128 + f) * 4096 + s_base + c8 * 8) = v;
    }
  }
}

// ---------------------------------------------------------------------------
// Flash attention, KV-split. Block: 64 q-rows (4 waves x 16), blockIdx.z picks
// a KV chunk of S_/nsplit. Swapped QK^T (P in registers), V pre-transposed.
// Emits UNNORMALIZED O + (m,l) per (split,row); combine() merges splits.
// ---------------------------------------------------------------------------
__global__ __launch_bounds__(256) void attn(const _Float16* __restrict__ qk,
                                            const _Float16* __restrict__ vt,
                                            float* __restrict__ pO,
                                            float* __restrict__ pml,
                                            int ntiles)
{
  __shared__ _Float16 Kl[64 * 128];     // [kv][d], rows XOR-swizzled (^row&15 granules)
  __shared__ _Float16 Vl[128 * 64];     // [f][kv], rows XOR-swizzled (^row&7 granules)
  const int tid  = threadIdx.x;
  const int lane = tid & 63, wid = tid >> 6;
  const int g = lane >> 4, l15 = lane & 15;
  const int b  = blockIdx.y;
  const int q0 = blockIdx.x * 64;
  const int split = blockIdx.z;
  const int kv_begin = split * (ntiles * 64);

  f16x8 qf[4];
  {
    const size_t qrow = (size_t)(b * S_ + q0 + wid * 16 + l15) * 256;
    #pragma unroll
    for (int kk = 0; kk < 4; ++kk)
      qf[kk] = *(const f16x8*)(qk + qrow + kk * 32 + g * 8);
  }

  f32x4 oacc[8] = {};
  float m_run = -1e30f, l_run = 0.f;

  for (int t = 0; t < ntiles; ++t) {
    const int kv0 = kv_begin + t * 64;
    #pragma unroll
    for (int it = 0; it < 4; ++it) {     // K tile [64][128]
      int G   = it * 256 + tid;
      int row = G >> 4;
      int cb  = (((G & 15) << 4)) ^ ((row & 15) << 4);
      const char* ga = (const char*)qk + (size_t)(b * S_ + kv0 + row) * 512 + 256 + cb;
      __builtin_amdgcn_global_load_lds(ga, (char*)Kl + (it * 256 + wid * 64) * 16, 16, 0, 0);
    }
    #pragma unroll
    for (int it = 0; it < 4; ++it) {     // V^T tile [128][64]
      int G  = it * 256 + tid;
      int f  = G >> 3, pc = G & 7;
      const char* ga = (const char*)vt + ((size_t)(b * 128 + f) * 4096 + kv0) * 2 +
                       (((pc ^ (f & 7)) << 4));
      __builtin_amdgcn_global_load_lds(ga, (char*)Vl + (it * 256 + wid * 64) * 16, 16, 0, 0);
    }
    __syncthreads();

    f32x4 sacc[4] = {};
    __builtin_amdgcn_s_setprio(1);
    #pragma unroll
    for (int kk = 0; kk < 4; ++kk)
      #pragma unroll
      for (int kvt = 0; kvt < 4; ++kvt) {
        int row = kvt * 16 + l15;
        f16x8 kf = *(const f16x8*)((const char*)Kl + row * 256 +
                                   ((kk * 64 + g * 16) ^ ((row & 15) << 4)));
        sacc[kvt] = __builtin_amdgcn_mfma_f32_16x16x32_f16(kf, qf[kk], sacc[kvt], 0, 0, 0);
      }
    __builtin_amdgcn_s_setprio(0);

    float sv[4][4];
    float mloc = -1e30f;
    #pragma unroll
    for (int kvt = 0; kvt < 4; ++kvt)
      #pragma unroll
      for (int r = 0; r < 4; ++r) {
        float s = sacc[kvt][r] * 0.03125f;      // 1/sqrt(1024)
        sv[kvt][r] = s;
        mloc = fmaxf(mloc, s);
      }
    mloc = fmaxf(mloc, __shfl_xor(mloc, 16));
    mloc = fmaxf(mloc, __shfl_xor(mloc, 32));
    float m_new = fmaxf(m_run, mloc);
    float corr  = __expf(m_run - m_new);
    float psum  = 0.f;
    _Float16 pb[4][4];
    #pragma unroll
    for (int kvt = 0; kvt < 4; ++kvt)
      #pragma unroll
      for (int r = 0; r < 4; ++r) {
        float p = __expf(sv[kvt][r] - m_new);
        psum += p;
        pb[kvt][r] = (_Float16)p;
      }
    psum += __shfl_xor(psum, 16);
    psum += __shfl_xor(psum, 32);
    l_run = l_run * corr + psum;
    m_run = m_new;

    #pragma unroll
    for (int r = 0; r < 4; ++r) {          // O lives at q = 4g+r: pull corr[4g+r]
      float cr = __builtin_bit_cast(float,
                   __builtin_amdgcn_ds_bpermute((((g << 2) + r) << 2),
                                                __builtin_bit_cast(int, corr)));
      #pragma unroll
      for (int ft = 0; ft < 8; ++ft) oacc[ft][r] *= cr;
    }

    f16x8 pa[2];
    #pragma unroll
    for (int kk = 0; kk < 2; ++kk)
      #pragma unroll
      for (int i = 0; i < 8; ++i)
        pa[kk][i] = pb[2 * kk + (i >> 2)][i & 3];

    __builtin_amdgcn_s_setprio(1);
    #pragma unroll
    for (int kk = 0; kk < 2; ++kk)
      #pragma unroll
      for (int ft = 0; ft < 8; ++ft) {
        int row = ft * 16 + l15;
        int swz = (row & 7) << 4;
        const char* rb = (const char*)Vl + row * 128;
        u32x2 w0 = *(const u32x2*)(rb + ((kk * 64 + g * 8     ) ^ swz));
        u32x2 w1 = *(const u32x2*)(rb + ((kk * 64 + g * 8 + 32) ^ swz));
        f16x8 vf;
        ((u32x2*)&vf)[0] = w0;
        ((u32x2*)&vf)[1] = w1;
        oacc[ft] = __builtin_amdgcn_mfma_f32_16x16x32_f16(pa[kk], vf, oacc[ft], 0, 0, 0);
      }
    __builtin_amdgcn_s_setprio(0);
    __syncthreads();
  }

  // emit unnormalized O and (m,l) per row
  #pragma unroll
  for (int r = 0; r < 4; ++r) {
    float mr = __builtin_bit_cast(float,
                 __builtin_amdgcn_ds_bpermute((((g << 2) + r) << 2),
                                              __builtin_bit_cast(int, m_run)));
    float lr = __builtin_bit_cast(float,
                 __builtin_amdgcn_ds_bpermute((((g << 2) + r) << 2),
                                              __builtin_bit_cast(int, l_run)));
    const int grow = b * S_ + q0 + wid * 16 + (g << 2) + r;
    float* od = pO + ((size_t)split * NROWS + grow) * 128;
    #pragma unroll
    for (int ft = 0; ft < 8; ++ft)
      od[ft * 16 + l15] = oacc[ft][r];
    if (l15 == 0)
      *(f32x2*)(pml + ((size_t)split * NROWS + grow) * 2) = f32x2{mr, lr};
  }
}

// ---------------------------------------------------------------------------
// Combine splits: out[row] = sum_s exp(m_s - M) O_s[row] / sum_s exp(m_s-M) l_s
// ---------------------------------------------------------------------------
__global__ __launch_bounds__(256) void combine(const float* __restrict__ pO,
                                               const float* __restrict__ pml,
                                               float* __restrict__ out,
                                               int nsplit)
{
  const int tid = threadIdx.x;
  const int row = blockIdx.x * 2 + (tid >> 7);
  const int col = tid & 127;

  float M = -1e30f;
  for (int s = 0; s < nsplit; ++s)
    M = fmaxf(M, pml[((size_t)s * NROWS + row) * 2]);
  float L = 0.f, acc = 0.f;
  for (int s = 0; s < nsplit; ++s) {
    f32x2 ml = *(const f32x2*)(pml + ((size_t)s * NROWS + row) * 2);
    float w = __expf(ml.x - M);
    L += ml.y * w;
    acc += pO[((size_t)s * NROWS + row) * 128 + col] * w;
  }
  out[(size_t)row * 128 + col] = acc / L;
}

extern "C" void kernel_launch(void* const* d_in, const int* in_sizes, int n_in,
                              void* d_out, int out_size, void* d_ws, size_t ws_size,
                              hipStream_t stream)
{
  (void)in_sizes; (void)n_in; (void)out_size;
  const float* x  = (const float*)d_in[0];
  const float* Wq = (const float*)d_in[1];
  const float* Wk = (const float*)d_in[2];
  const float* Wv = (const float*)d_in[3];

  char* ws = (char*)d_ws;
  _Float16* qkbuf = (_Float16*)ws;                      // 16384x256 f16 = 8.39 MB
  _Float16* vtbuf = (_Float16*)(ws + (size_t)NROWS * 256 * 2);  // 4x128x4096 f16 = 4 MB
  const size_t base = (size_t)NROWS * 256 * 2 + (size_t)4 * 128 * 4096 * 2;
  const size_t perO  = (size_t)NROWS * 128 * 4;         // 8.39 MB / split
  const size_t perML = (size_t)NROWS * 2 * 4;           // 128 KB / split

  int nsplit = 4;
  while (nsplit > 1 && base + (size_t)nsplit * (perO + perML) > ws_size) nsplit >>= 1;

  float* pO  = (float*)(ws + base);
  float* pml = (float*)(ws + base + (size_t)nsplit * perO);
  float* out = (float*)d_out;

  dim3 gg(128, 3);
  gemm_qkv<<<gg, 256, 0, stream>>>(x, Wq, Wk, Wv, qkbuf, vtbuf);
  dim3 ga(64, 4, nsplit);
  attn<<<ga, 256, 0, stream>>>(qkbuf, vtbuf, pO, pml, 64 / nsplit);
  combine<<<NROWS / 2, 256, 0, stream>>>(pO, pml, out, nsplit);
}

// Round 8
// 102.086 us; speedup vs baseline: 1.6877x; 1.3169x over previous
//
#include <hip/hip_runtime.h>
#include <stdint.h>

typedef __attribute__((ext_vector_type(8))) _Float16 f16x8;
typedef __attribute__((ext_vector_type(4))) float f32x4;
typedef __attribute__((ext_vector_type(2))) float f32x2;

#define S_ 4096
#define D_ 1024
#define NROWS 16384          // B*S

// ---------------------------------------------------------------------------
// Projections. qk[s][256] (f16) = [x@Wq^T | x@Wk^T]; vt = V^T in a granule-
// permuted layout: row f (8192B), byte  (s/64)*128 + q*16 + h*8 + j*2  for
// s%64 = kk*32 + h*16 + q*4 + j  -> one 16B granule == one PV B-fragment.
// ---------------------------------------------------------------------------
__global__ __launch_bounds__(256) void gemm_qkv(
    const float* __restrict__ x, const float* __restrict__ Wq,
    const float* __restrict__ Wk, const float* __restrict__ Wv,
    _Float16* __restrict__ qk, _Float16* __restrict__ vt)
{
  __shared__ char smem[32768];
  float* At = (float*)smem;             // [128][32] f32
  float* Bt = (float*)(smem + 16384);   // [128][32] f32
  const int tid  = threadIdx.x;
  const int lane = tid & 63, wid = tid >> 6;
  const int g = lane >> 4, l15 = lane & 15;
  const int wr = wid >> 1, wc = wid & 1;
  const int m0 = blockIdx.x * 128;
  const int by = blockIdx.y;
  const float* W = (by == 0) ? Wq : ((by == 1) ? Wk : Wv);

  f32x4 acc[4][4] = {};

  for (int k0 = 0; k0 < D_; k0 += 32) {
    #pragma unroll
    for (int it = 0; it < 4; ++it) {
      int G   = it * 256 + tid;          // 16B granule, 0..1023
      int row = G >> 3;
      int cb  = ((G & 7) ^ (row & 7)) << 4;
      const char* ga = (const char*)x + (size_t)(m0 + row) * 4096 + k0 * 4 + cb;
      const char* gb = (const char*)W + (size_t)row * 4096 + k0 * 4 + cb;
      __builtin_amdgcn_global_load_lds(ga, (char*)At + (it * 256 + wid * 64) * 16, 16, 0, 0);
      __builtin_amdgcn_global_load_lds(gb, (char*)Bt + (it * 256 + wid * 64) * 16, 16, 0, 0);
    }
    __syncthreads();

    f16x8 af[4], bg[4];
    #pragma unroll
    for (int mt = 0; mt < 4; ++mt) {
      int row = wr * 64 + mt * 16 + l15;
      const char* base = (const char*)At + row * 128;
      f32x4 a0 = *(const f32x4*)(base + (((2 * g    ) ^ (row & 7)) << 4));
      f32x4 a1 = *(const f32x4*)(base + (((2 * g + 1) ^ (row & 7)) << 4));
      #pragma unroll
      for (int i = 0; i < 4; ++i) { af[mt][i] = (_Float16)a0[i]; af[mt][i + 4] = (_Float16)a1[i]; }
    }
    #pragma unroll
    for (int nt = 0; nt < 4; ++nt) {
      int row = wc * 64 + nt * 16 + l15;
      const char* base = (const char*)Bt + row * 128;
      f32x4 b0 = *(const f32x4*)(base + (((2 * g    ) ^ (row & 7)) << 4));
      f32x4 b1 = *(const f32x4*)(base + (((2 * g + 1) ^ (row & 7)) << 4));
      #pragma unroll
      for (int i = 0; i < 4; ++i) { bg[nt][i] = (_Float16)b0[i]; bg[nt][i + 4] = (_Float16)b1[i]; }
    }

    __builtin_amdgcn_s_setprio(1);
    #pragma unroll
    for (int mt = 0; mt < 4; ++mt)
      #pragma unroll
      for (int nt = 0; nt < 4; ++nt)
        acc[mt][nt] = __builtin_amdgcn_mfma_f32_16x16x32_f16(af[mt], bg[nt], acc[mt][nt], 0, 0, 0);
    __builtin_amdgcn_s_setprio(0);
    __syncthreads();
  }

  if (by < 2) {
    // D layout (m89): col = lane&15, row = 4*(lane>>4)+reg
    #pragma unroll
    for (int mt = 0; mt < 4; ++mt)
      #pragma unroll
      for (int nt = 0; nt < 4; ++nt)
        #pragma unroll
        for (int r = 0; r < 4; ++r) {
          int row = m0 + wr * 64 + mt * 16 + (g << 2) + r;
          int col = by * 128 + wc * 64 + nt * 16 + l15;
          qk[(size_t)row * 256 + col] = (_Float16)acc[mt][nt][r];
        }
  } else {
    // V: transpose through LDS, then granule-permuted f16x8 stores
    _Float16* T = (_Float16*)smem;      // [128 s][128 f]
    #pragma unroll
    for (int mt = 0; mt < 4; ++mt)
      #pragma unroll
      for (int nt = 0; nt < 4; ++nt)
        #pragma unroll
        for (int r = 0; r < 4; ++r)
          T[(wr * 64 + mt * 16 + (g << 2) + r) * 128 + wc * 64 + nt * 16 + l15] =
              (_Float16)acc[mt][nt][r];
    __syncthreads();
    const int b = m0 >> 12, s_base = m0 & 4095;
    #pragma unroll
    for (int it = 0; it < 8; ++it) {
      int Wn = it * 256 + tid;           // 0..2047
      int f = Wn >> 4, S64 = (Wn >> 3) & 1, gran = Wn & 7;
      int kk = gran >> 2, q = gran & 3;
      f16x8 v;
      #pragma unroll
      for (int i = 0; i < 8; ++i) {
        int h = i >> 2, j = i & 3;
        int sl = S64 * 64 + kk * 32 + h * 16 + q * 4 + j;
        v[i] = T[sl * 128 + f];
      }
      *(f16x8*)((char*)vt + (size_t)(b * 128 + f) * 8192 + s_base * 2 + S64 * 128 + gran * 16) = v;
    }
  }
}

// ---------------------------------------------------------------------------
// Flash attention, KV-split, 8 waves x 16 q-rows, double-buffered K/V with
// prefetch-before-compute. Swapped QK^T; P packed straight into pa; V frag =
// one ds_read_b128 from the permuted vt tile. Defer-max skips O-rescale.
// Emits NORMALIZED O (f16) + (m,l) per (split,row).
// ---------------------------------------------------------------------------
__global__ __launch_bounds__(512, 4) void attn(const _Float16* __restrict__ qk,
                                               const _Float16* __restrict__ vt,
                                               _Float16* __restrict__ pO,
                                               float* __restrict__ pml,
                                               int ntiles)
{
  __shared__ _Float16 K0l[64 * 128], K1l[64 * 128];   // 16 KB each, XOR-swz rows
  __shared__ _Float16 V0l[64 * 128], V1l[64 * 128];   // permuted-granule tiles
  const int tid  = threadIdx.x;
  const int lane = tid & 63, wid = tid >> 6;
  const int g = lane >> 4, l15 = lane & 15;
  const int b  = blockIdx.y;
  const int q0 = blockIdx.x * 128;
  const int split = blockIdx.z;
  const int kv_begin = split * (ntiles * 64);

  f16x8 qf[4];
  {
    const size_t qrow = (size_t)(b * S_ + q0 + wid * 16 + l15) * 256;
    #pragma unroll
    for (int kk = 0; kk < 4; ++kk)
      qf[kk] = *(const f16x8*)(qk + qrow + kk * 32 + g * 8);
  }

  // per-thread staging source pointers (2 granules K, 2 granules V)
  const char* gK[2]; const char* gV[2];
  #pragma unroll
  for (int it = 0; it < 2; ++it) {
    int G = it * 512 + tid;
    int row = G >> 4, ch = G & 15;
    gK[it] = (const char*)qk + (size_t)(b * S_ + kv_begin + row) * 512 + 256 +
             (((ch << 4)) ^ ((row & 15) << 4));
    int f = G >> 3, c = G & 7;
    gV[it] = (const char*)vt + (size_t)(b * 128 + f) * 8192 + (kv_begin >> 6) * 128 +
             ((c ^ (f & 7)) << 4);
  }

#define STAGE(Kb, Vb) do {                                                          \
    _Pragma("unroll")                                                               \
    for (int it_ = 0; it_ < 2; ++it_) {                                             \
      __builtin_amdgcn_global_load_lds(gK[it_],                                     \
          (char*)(Kb) + (it_ * 512 + wid * 64) * 16, 16, 0, 0);                     \
      __builtin_amdgcn_global_load_lds(gV[it_],                                     \
          (char*)(Vb) + (it_ * 512 + wid * 64) * 16, 16, 0, 0);                     \
    }                                                                               \
    gK[0] += 32768; gK[1] += 32768; gV[0] += 128; gV[1] += 128;                     \
  } while (0)

  f32x4 oacc[8] = {};
  float m_run = -1e30f, l_run = 0.f;

#define COMPUTE(Kb, Vb) do {                                                        \
    f32x4 sacc[4] = {};                                                             \
    __builtin_amdgcn_s_setprio(1);                                                  \
    _Pragma("unroll")                                                               \
    for (int kk = 0; kk < 4; ++kk) {                                                \
      const char* kb = (const char*)(Kb) + l15 * 256 +                              \
                       (((kk << 6) | (g << 4)) ^ (l15 << 4));                       \
      _Pragma("unroll")                                                             \
      for (int kvt = 0; kvt < 4; ++kvt) {                                           \
        f16x8 kf = *(const f16x8*)(kb + kvt * 4096);                                \
        sacc[kvt] = __builtin_amdgcn_mfma_f32_16x16x32_f16(kf, qf[kk], sacc[kvt],   \
                                                           0, 0, 0);                \
      }                                                                             \
    }                                                                               \
    __builtin_amdgcn_s_setprio(0);                                                  \
    float pmax = -1e30f;                                                            \
    _Pragma("unroll")                                                               \
    for (int kvt = 0; kvt < 4; ++kvt)                                               \
      _Pragma("unroll")                                                             \
      for (int r = 0; r < 4; ++r) {                                                 \
        float s = sacc[kvt][r] * 0.03125f;                                          \
        sacc[kvt][r] = s;                                                           \
        pmax = fmaxf(pmax, s);                                                      \
      }                                                                             \
    pmax = fmaxf(pmax, __shfl_xor(pmax, 16));                                       \
    pmax = fmaxf(pmax, __shfl_xor(pmax, 32));                                       \
    if (!__all(pmax - m_run <= 5.5f)) {                                             \
      float m_new = fmaxf(m_run, pmax);                                             \
      float corr  = __expf(m_run - m_new);                                          \
      l_run *= corr;                                                                \
      m_run  = m_new;                                                               \
      _Pragma("unroll")                                                             \
      for (int r = 0; r < 4; ++r) {                                                 \
        float cr = __builtin_bit_cast(float,                                        \
            __builtin_amdgcn_ds_bpermute((((g << 2) + r) << 2),                     \
                                         __builtin_bit_cast(int, corr)));           \
        _Pragma("unroll")                                                           \
        for (int ft = 0; ft < 8; ++ft) oacc[ft][r] *= cr;                           \
      }                                                                             \
    }                                                                               \
    float psum = 0.f;                                                               \
    f16x8 pa[2];                                                                    \
    _Pragma("unroll")                                                               \
    for (int k2 = 0; k2 < 2; ++k2)                                                  \
      _Pragma("unroll")                                                             \
      for (int i = 0; i < 8; ++i) {                                                 \
        float p = __expf(sacc[2 * k2 + (i >> 2)][i & 3] - m_run);                   \
        psum += p;                                                                  \
        pa[k2][i] = (_Float16)p;                                                    \
      }                                                                             \
    psum += __shfl_xor(psum, 16);                                                   \
    psum += __shfl_xor(psum, 32);                                                   \
    l_run += psum;                                                                  \
    __builtin_amdgcn_s_setprio(1);                                                  \
    _Pragma("unroll")                                                               \
    for (int k2 = 0; k2 < 2; ++k2) {                                                \
      const char* vb = (const char*)(Vb) + l15 * 128 +                              \
                       (((k2 << 6) | (g << 4)) ^ ((l15 & 7) << 4));                 \
      _Pragma("unroll")                                                             \
      for (int ft = 0; ft < 8; ++ft) {                                              \
        f16x8 vf = *(const f16x8*)(vb + ft * 2048);                                 \
        oacc[ft] = __builtin_amdgcn_mfma_f32_16x16x32_f16(pa[k2], vf, oacc[ft],     \
                                                          0, 0, 0);                 \
      }                                                                             \
    }                                                                               \
    __builtin_amdgcn_s_setprio(0);                                                  \
  } while (0)

  STAGE(K0l, V0l);                 // tile 0
  __syncthreads();
  for (int t = 0; t < ntiles; t += 2) {
    STAGE(K1l, V1l);               // tile t+1 (ntiles is even)
    COMPUTE(K0l, V0l);
    __syncthreads();
    if (t + 2 < ntiles) STAGE(K0l, V0l);   // tile t+2
    COMPUTE(K1l, V1l);
    __syncthreads();
  }

  // normalized O (f16) + (m,l)
  #pragma unroll
  for (int r = 0; r < 4; ++r) {
    float mr = __builtin_bit_cast(float,
                 __builtin_amdgcn_ds_bpermute((((g << 2) + r) << 2),
                                              __builtin_bit_cast(int, m_run)));
    float lr = __builtin_bit_cast(float,
                 __builtin_amdgcn_ds_bpermute((((g << 2) + r) << 2),
                                              __builtin_bit_cast(int, l_run)));
    float inv = 1.f / lr;
    const int grow = b * S_ + q0 + wid * 16 + (g << 2) + r;
    _Float16* od = pO + ((size_t)split * NROWS + grow) * 128;
    #pragma unroll
    for (int ft = 0; ft < 8; ++ft)
      od[ft * 16 + l15] = (_Float16)(oacc[ft][r] * inv);
    if (l15 == 0)
      *(f32x2*)(pml + ((size_t)split * NROWS + grow) * 2) = f32x2{mr, lr};
  }
#undef STAGE
#undef COMPUTE
}

// ---------------------------------------------------------------------------
// Combine: out = sum_s w_s l_s O'_s / sum_s w_s l_s,  w_s = exp(m_s - M)
// ---------------------------------------------------------------------------
__global__ __launch_bounds__(256) void combine(const _Float16* __restrict__ pO,
                                               const float* __restrict__ pml,
                                               float* __restrict__ out,
                                               int nsplit)
{
  const int tid = threadIdx.x;
  const int row = blockIdx.x * 2 + (tid >> 7);
  const int col = tid & 127;

  float M = -1e30f;
  for (int s = 0; s < nsplit; ++s)
    M = fmaxf(M, pml[((size_t)s * NROWS + row) * 2]);
  float den = 0.f, num = 0.f;
  for (int s = 0; s < nsplit; ++s) {
    f32x2 ml = *(const f32x2*)(pml + ((size_t)s * NROWS + row) * 2);
    float w = __expf(ml.x - M) * ml.y;
    den += w;
    num += w * (float)pO[((size_t)s * NROWS + row) * 128 + col];
  }
  out[(size_t)row * 128 + col] = num / den;
}

extern "C" void kernel_launch(void* const* d_in, const int* in_sizes, int n_in,
                              void* d_out, int out_size, void* d_ws, size_t ws_size,
                              hipStream_t stream)
{
  (void)in_sizes; (void)n_in; (void)out_size;
  const float* x  = (const float*)d_in[0];
  const float* Wq = (const float*)d_in[1];
  const float* Wk = (const float*)d_in[2];
  const float* Wv = (const float*)d_in[3];

  char* ws = (char*)d_ws;
  _Float16* qkbuf = (_Float16*)ws;                               // 8.39 MB
  _Float16* vtbuf = (_Float16*)(ws + (size_t)NROWS * 256 * 2);   // 4 MB
  const size_t base  = (size_t)NROWS * 256 * 2 + (size_t)4 * 128 * 4096 * 2;
  const size_t perO  = (size_t)NROWS * 128 * 2;                  // 4.19 MB / split (f16)
  const size_t perML = (size_t)NROWS * 2 * 4;                    // 128 KB / split

  int nsplit = 4;
  while (nsplit > 1 && base + (size_t)nsplit * (perO + perML) > ws_size) nsplit >>= 1;

  _Float16* pO  = (_Float16*)(ws + base);
  float*    pml = (float*)(ws + base + (size_t)nsplit * perO);
  float*    out = (float*)d_out;

  dim3 gg(128, 3);
  gemm_qkv<<<gg, 256, 0, stream>>>(x, Wq, Wk, Wv, qkbuf, vtbuf);
  dim3 ga(S_ / 128, 4, nsplit);
  attn<<<ga, 512, 0, stream>>>(qkbuf, vtbuf, pO, pml, 64 / nsplit);
  combine<<<NROWS / 2, 256, 0, stream>>>(pO, pml, out, nsplit);
}

// Round 12
// 92.439 us; speedup vs baseline: 1.8638x; 1.1044x over previous
//
#include <hip/hip_runtime.h>
#include <stdint.h>

typedef __attribute__((ext_vector_type(8))) _Float16 f16x8;
typedef __attribute__((ext_vector_type(4))) float f32x4;
typedef __attribute__((ext_vector_type(2))) float f32x2;

#define S_ 4096
#define D_ 1024
#define NROWS 16384          // B*S

// ---------------------------------------------------------------------------
// Projections, f32 inputs staged via global_load_lds (granule swizzle ^row&7),
// f16 conversion at fragment load. 64x128 tile -> grid 256x3 = 768 blocks =
// 3 blocks/CU. BK=32, 4 waves (each a 64x32 N-quarter), double-buffered LDS
// (48 KB) with STAGE-before-COMPUTE prefetch.
// qk[s][256] = [Q|K]; vt = V^T granule-permuted: granule (kk*4+q) of row f,
// s-chunk sc holds V[sc*64 + kk*32 + h*16 + q*4 + j][f] at slot 4h+j.
// ---------------------------------------------------------------------------
__global__ __launch_bounds__(256) void gemm_qkv(
    const float* __restrict__ x, const float* __restrict__ Wq,
    const float* __restrict__ Wk, const float* __restrict__ Wv,
    _Float16* __restrict__ qk, _Float16* __restrict__ vt)
{
  __shared__ char smem[49152];          // A0 0..8K | B0 8..24K | A1 24..32K | B1 32..48K
  char* Ab[2] = { smem,        smem + 24576 };
  char* Bb[2] = { smem + 8192, smem + 32768 };
  const int tid  = threadIdx.x;
  const int lane = tid & 63, wid = tid >> 6;
  const int g = lane >> 4, l15 = lane & 15;
  const int m0 = blockIdx.x * 64;
  const int by = blockIdx.y;
  const float* W = (by == 0) ? Wq : ((by == 1) ? Wk : Wv);

  // staging source pointers: A 64x32 f32 = 512 granules (2/thread),
  // B 128x32 f32 = 1024 granules (4/thread); source granule XOR ^(row&7).
  // NOTE: W is already the by-selected 128x1024 matrix -> row offset is just
  // `row` (r10's by*128+row read 0.5-1.5 MB OOB -> memory fault).
  const char* pA[2]; const char* pB[4];
  #pragma unroll
  for (int it = 0; it < 2; ++it) {
    int G = it * 256 + tid, row = G >> 3, gg = (G & 7) ^ (row & 7);
    pA[it] = (const char*)x + (size_t)(m0 + row) * 4096 + gg * 16;
  }
  #pragma unroll
  for (int it = 0; it < 4; ++it) {
    int G = it * 256 + tid, row = G >> 3, gg = (G & 7) ^ (row & 7);
    pB[it] = (const char*)W + (size_t)row * 4096 + gg * 16;
  }

#define GSTAGE(bi) do {                                                        \
    _Pragma("unroll")                                                          \
    for (int it_ = 0; it_ < 2; ++it_) {                                        \
      __builtin_amdgcn_global_load_lds(pA[it_],                                \
          Ab[bi] + (it_ * 256 + wid * 64) * 16, 16, 0, 0);                     \
      pA[it_] += 128;                                                          \
    }                                                                          \
    _Pragma("unroll")                                                          \
    for (int it_ = 0; it_ < 4; ++it_) {                                        \
      __builtin_amdgcn_global_load_lds(pB[it_],                                \
          Bb[bi] + (it_ * 256 + wid * 64) * 16, 16, 0, 0);                     \
      pB[it_] += 128;                                                          \
    }                                                                          \
  } while (0)

  f32x4 acc[4][2] = {};

#define GCOMPUTE(bi) do {                                                      \
    f16x8 af[4], bg[2];                                                        \
    _Pragma("unroll")                                                          \
    for (int mt = 0; mt < 4; ++mt) {                                           \
      int row = mt * 16 + l15;                                                 \
      const char* base = Ab[bi] + row * 128;                                   \
      f32x4 a0 = *(const f32x4*)(base + (((2 * g    ) ^ (row & 7)) << 4));     \
      f32x4 a1 = *(const f32x4*)(base + (((2 * g + 1) ^ (row & 7)) << 4));     \
      _Pragma("unroll")                                                        \
      for (int i = 0; i < 4; ++i) {                                            \
        af[mt][i] = (_Float16)a0[i]; af[mt][i + 4] = (_Float16)a1[i];          \
      }                                                                        \
    }                                                                          \
    _Pragma("unroll")                                                          \
    for (int nt = 0; nt < 2; ++nt) {                                           \
      int row = wid * 32 + nt * 16 + l15;                                      \
      const char* base = Bb[bi] + row * 128;                                   \
      f32x4 b0 = *(const f32x4*)(base + (((2 * g    ) ^ (row & 7)) << 4));     \
      f32x4 b1 = *(const f32x4*)(base + (((2 * g + 1) ^ (row & 7)) << 4));     \
      _Pragma("unroll")                                                        \
      for (int i = 0; i < 4; ++i) {                                            \
        bg[nt][i] = (_Float16)b0[i]; bg[nt][i + 4] = (_Float16)b1[i];          \
      }                                                                        \
    }                                                                          \
    __builtin_amdgcn_s_setprio(1);                                             \
    _Pragma("unroll")                                                          \
    for (int mt = 0; mt < 4; ++mt)                                             \
      _Pragma("unroll")                                                        \
      for (int nt = 0; nt < 2; ++nt)                                           \
        acc[mt][nt] = __builtin_amdgcn_mfma_f32_16x16x32_f16(af[mt], bg[nt],   \
                                                             acc[mt][nt], 0, 0, 0); \
    __builtin_amdgcn_s_setprio(0);                                             \
  } while (0)

  GSTAGE(0);
  __syncthreads();
  for (int t = 0; t < 32; t += 2) {
    GSTAGE(1);
    GCOMPUTE(0);
    __syncthreads();
    if (t + 2 < 32) GSTAGE(0);
    GCOMPUTE(1);
    __syncthreads();
  }

  if (by < 2) {
    // D layout (m89): col = l15, row = 4g + r
    #pragma unroll
    for (int mt = 0; mt < 4; ++mt)
      #pragma unroll
      for (int nt = 0; nt < 2; ++nt)
        #pragma unroll
        for (int r = 0; r < 4; ++r) {
          int row = m0 + mt * 16 + (g << 2) + r;
          int col = by * 128 + wid * 32 + nt * 16 + l15;
          qk[(size_t)row * 256 + col] = (_Float16)acc[mt][nt][r];
        }
  } else {
    // V: transpose 64(s) x 128(f) through LDS, then granule-permuted stores
    _Float16* T = (_Float16*)smem;      // [64 s][128 f] = 16 KB (tiles dead)
    #pragma unroll
    for (int mt = 0; mt < 4; ++mt)
      #pragma unroll
      for (int nt = 0; nt < 2; ++nt)
        #pragma unroll
        for (int r = 0; r < 4; ++r)
          T[(mt * 16 + (g << 2) + r) * 128 + wid * 32 + nt * 16 + l15] =
              (_Float16)acc[mt][nt][r];
    __syncthreads();
    const int b = m0 >> 12, s_base = m0 & 4095;
    #pragma unroll
    for (int it = 0; it < 4; ++it) {
      int Wn = it * 256 + tid;           // 0..1023
      int f = Wn >> 3, gran = Wn & 7;
      int kk = gran >> 2, q = gran & 3;
      f16x8 v;
      #pragma unroll
      for (int i = 0; i < 8; ++i) {
        int h = i >> 2, j = i & 3;
        v[i] = T[(kk * 32 + h * 16 + q * 4 + j) * 128 + f];
      }
      *(f16x8*)((char*)vt + (size_t)(b * 128 + f) * 8192 + s_base * 2 + gran * 16) = v;
    }
  }
#undef GSTAGE
#undef GCOMPUTE
}

// ---------------------------------------------------------------------------
// Flash attention (r8-proven, unchanged). KV-split, 8 waves x 16 q-rows,
// double-buffered K/V, swapped QK^T, permuted-V single-b128 fragments,
// defer-max. Emits NORMALIZED O (f16) + (m,l).
// ---------------------------------------------------------------------------
__global__ __launch_bounds__(512, 4) void attn(const _Float16* __restrict__ qk,
                                               const _Float16* __restrict__ vt,
                                               _Float16* __restrict__ pO,
                                               float* __restrict__ pml,
                                               int ntiles)
{
  __shared__ _Float16 K0l[64 * 128], K1l[64 * 128];
  __shared__ _Float16 V0l[64 * 128], V1l[64 * 128];
  const int tid  = threadIdx.x;
  const int lane = tid & 63, wid = tid >> 6;
  const int g = lane >> 4, l15 = lane & 15;
  const int b  = blockIdx.y;
  const int q0 = blockIdx.x * 128;
  const int split = blockIdx.z;
  const int kv_begin = split * (ntiles * 64);

  f16x8 qf[4];
  {
    const size_t qrow = (size_t)(b * S_ + q0 + wid * 16 + l15) * 256;
    #pragma unroll
    for (int kk = 0; kk < 4; ++kk)
      qf[kk] = *(const f16x8*)(qk + qrow + kk * 32 + g * 8);
  }

  const char* gK[2]; const char* gV[2];
  #pragma unroll
  for (int it = 0; it < 2; ++it) {
    int G = it * 512 + tid;
    int row = G >> 4, ch = G & 15;
    gK[it] = (const char*)qk + (size_t)(b * S_ + kv_begin + row) * 512 + 256 +
             (((ch << 4)) ^ ((row & 15) << 4));
    int f = G >> 3, c = G & 7;
    gV[it] = (const char*)vt + (size_t)(b * 128 + f) * 8192 + (kv_begin >> 6) * 128 +
             ((c ^ (f & 7)) << 4);
  }

#define STAGE(Kb, Vb) do {                                                          \
    _Pragma("unroll")                                                               \
    for (int it_ = 0; it_ < 2; ++it_) {                                             \
      __builtin_amdgcn_global_load_lds(gK[it_],                                     \
          (char*)(Kb) + (it_ * 512 + wid * 64) * 16, 16, 0, 0);                     \
      __builtin_amdgcn_global_load_lds(gV[it_],                                     \
          (char*)(Vb) + (it_ * 512 + wid * 64) * 16, 16, 0, 0);                     \
    }                                                                               \
    gK[0] += 32768; gK[1] += 32768; gV[0] += 128; gV[1] += 128;                     \
  } while (0)

  f32x4 oacc[8] = {};
  float m_run = -1e30f, l_run = 0.f;

#define COMPUTE(Kb, Vb) do {                                                        \
    f32x4 sacc[4] = {};                                                             \
    __builtin_amdgcn_s_setprio(1);                                                  \
    _Pragma("unroll")                                                               \
    for (int kk = 0; kk < 4; ++kk) {                                                \
      const char* kb = (const char*)(Kb) + l15 * 256 +                              \
                       (((kk << 6) | (g << 4)) ^ (l15 << 4));                       \
      _Pragma("unroll")                                                             \
      for (int kvt = 0; kvt < 4; ++kvt) {                                           \
        f16x8 kf = *(const f16x8*)(kb + kvt * 4096);                                \
        sacc[kvt] = __builtin_amdgcn_mfma_f32_16x16x32_f16(kf, qf[kk], sacc[kvt],   \
                                                           0, 0, 0);                \
      }                                                                             \
    }                                                                               \
    __builtin_amdgcn_s_setprio(0);                                                  \
    float pmax = -1e30f;                                                            \
    _Pragma("unroll")                                                               \
    for (int kvt = 0; kvt < 4; ++kvt)                                               \
      _Pragma("unroll")                                                             \
      for (int r = 0; r < 4; ++r) {                                                 \
        float s = sacc[kvt][r] * 0.03125f;                                          \
        sacc[kvt][r] = s;                                                           \
        pmax = fmaxf(pmax, s);                                                      \
      }                                                                             \
    pmax = fmaxf(pmax, __shfl_xor(pmax, 16));                                       \
    pmax = fmaxf(pmax, __shfl_xor(pmax, 32));                                       \
    if (!__all(pmax - m_run <= 5.5f)) {                                             \
      float m_new = fmaxf(m_run, pmax);                                             \
      float corr  = __expf(m_run - m_new);                                          \
      l_run *= corr;                                                                \
      m_run  = m_new;                                                               \
      _Pragma("unroll")                                                             \
      for (int r = 0; r < 4; ++r) {                                                 \
        float cr = __builtin_bit_cast(float,                                        \
            __builtin_amdgcn_ds_bpermute((((g << 2) + r) << 2),                     \
                                         __builtin_bit_cast(int, corr)));           \
        _Pragma("unroll")                                                           \
        for (int ft = 0; ft < 8; ++ft) oacc[ft][r] *= cr;                           \
      }                                                                             \
    }                                                                               \
    float psum = 0.f;                                                               \
    f16x8 pa[2];                                                                    \
    _Pragma("unroll")                                                               \
    for (int k2 = 0; k2 < 2; ++k2)                                                  \
      _Pragma("unroll")                                                             \
      for (int i = 0; i < 8; ++i) {                                                 \
        float p = __expf(sacc[2 * k2 + (i >> 2)][i & 3] - m_run);                   \
        psum += p;                                                                  \
        pa[k2][i] = (_Float16)p;                                                    \
      }                                                                             \
    psum += __shfl_xor(psum, 16);                                                   \
    psum += __shfl_xor(psum, 32);                                                   \
    l_run += psum;                                                                  \
    __builtin_amdgcn_s_setprio(1);                                                  \
    _Pragma("unroll")                                                               \
    for (int k2 = 0; k2 < 2; ++k2) {                                                \
      const char* vb = (const char*)(Vb) + l15 * 128 +                              \
                       (((k2 << 6) | (g << 4)) ^ ((l15 & 7) << 4));                 \
      _Pragma("unroll")                                                             \
      for (int ft = 0; ft < 8; ++ft) {                                              \
        f16x8 vf = *(const f16x8*)(vb + ft * 2048);                                 \
        oacc[ft] = __builtin_amdgcn_mfma_f32_16x16x32_f16(pa[k2], vf, oacc[ft],     \
                                                          0, 0, 0);                 \
      }                                                                             \
    }                                                                               \
    __builtin_amdgcn_s_setprio(0);                                                  \
  } while (0)

  STAGE(K0l, V0l);
  __syncthreads();
  for (int t = 0; t < ntiles; t += 2) {
    STAGE(K1l, V1l);
    COMPUTE(K0l, V0l);
    __syncthreads();
    if (t + 2 < ntiles) STAGE(K0l, V0l);
    COMPUTE(K1l, V1l);
    __syncthreads();
  }

  #pragma unroll
  for (int r = 0; r < 4; ++r) {
    float mr = __builtin_bit_cast(float,
                 __builtin_amdgcn_ds_bpermute((((g << 2) + r) << 2),
                                              __builtin_bit_cast(int, m_run)));
    float lr = __builtin_bit_cast(float,
                 __builtin_amdgcn_ds_bpermute((((g << 2) + r) << 2),
                                              __builtin_bit_cast(int, l_run)));
    float inv = 1.f / lr;
    const int grow = b * S_ + q0 + wid * 16 + (g << 2) + r;
    _Float16* od = pO + ((size_t)split * NROWS + grow) * 128;
    #pragma unroll
    for (int ft = 0; ft < 8; ++ft)
      od[ft * 16 + l15] = (_Float16)(oacc[ft][r] * inv);
    if (l15 == 0)
      *(f32x2*)(pml + ((size_t)split * NROWS + grow) * 2) = f32x2{mr, lr};
  }
#undef STAGE
#undef COMPUTE
}

// ---------------------------------------------------------------------------
// Combine: out = sum_s w_s l_s O'_s / sum_s w_s l_s,  w_s = exp(m_s - M)
// ---------------------------------------------------------------------------
__global__ __launch_bounds__(256) void combine(const _Float16* __restrict__ pO,
                                               const float* __restrict__ pml,
                                               float* __restrict__ out,
                                               int nsplit)
{
  const int tid = threadIdx.x;
  const int row = blockIdx.x * 2 + (tid >> 7);
  const int col = tid & 127;

  float M = -1e30f;
  for (int s = 0; s < nsplit; ++s)
    M = fmaxf(M, pml[((size_t)s * NROWS + row) * 2]);
  float den = 0.f, num = 0.f;
  for (int s = 0; s < nsplit; ++s) {
    f32x2 ml = *(const f32x2*)(pml + ((size_t)s * NROWS + row) * 2);
    float w = __expf(ml.x - M) * ml.y;
    den += w;
    num += w * (float)pO[((size_t)s * NROWS + row) * 128 + col];
  }
  out[(size_t)row * 128 + col] = num / den;
}

extern "C" void kernel_launch(void* const* d_in, const int* in_sizes, int n_in,
                              void* d_out, int out_size, void* d_ws, size_t ws_size,
                              hipStream_t stream)
{
  (void)in_sizes; (void)n_in; (void)out_size;
  const float* x  = (const float*)d_in[0];
  const float* Wq = (const float*)d_in[1];
  const float* Wk = (const float*)d_in[2];
  const float* Wv = (const float*)d_in[3];

  char* ws = (char*)d_ws;
  _Float16* qkbuf = (_Float16*)ws;                               // 8.39 MB
  _Float16* vtbuf = (_Float16*)(ws + (size_t)NROWS * 256 * 2);   // 4.19 MB
  const size_t base  = (size_t)NROWS * 256 * 2 + (size_t)4 * 128 * 4096 * 2;
  const size_t perO  = (size_t)NROWS * 128 * 2;                  // 4.19 MB / split (f16)
  const size_t perML = (size_t)NROWS * 2 * 4;                    // 128 KB / split

  int nsplit = 4;
  while (nsplit > 1 && base + (size_t)nsplit * (perO + perML) > ws_size) nsplit >>= 1;

  _Float16* pO  = (_Float16*)(ws + base);
  float*    pml = (float*)(ws + base + (size_t)nsplit * perO);
  float*    out = (float*)d_out;

  dim3 gg(256, 3);
  gemm_qkv<<<gg, 256, 0, stream>>>(x, Wq, Wk, Wv, qkbuf, vtbuf);
  dim3 ga(S_ / 128, 4, nsplit);
  attn<<<ga, 512, 0, stream>>>(qkbuf, vtbuf, pO, pml, 64 / nsplit);
  combine<<<NROWS / 2, 256, 0, stream>>>(pO, pml, out, nsplit);
}

// Round 13
// 91.795 us; speedup vs baseline: 1.8769x; 1.0070x over previous
//
#include <hip/hip_runtime.h>
#include <stdint.h>

typedef __attribute__((ext_vector_type(8))) _Float16 f16x8;
typedef __attribute__((ext_vector_type(4))) float f32x4;
typedef __attribute__((ext_vector_type(2))) float f32x2;

#define S_ 4096
#define D_ 1024
#define NROWS 16384          // B*S

// ---------------------------------------------------------------------------
// Tiny pre-pass: Wq|Wk|Wv (3 x 128 x 1024 f32 = 1.5 MB) -> concatenated f16.
// 192 blocks x 256 thr x 8 elems = exactly 393216 elements.
// ---------------------------------------------------------------------------
__global__ __launch_bounds__(256) void cvtw(
    const float* __restrict__ Wq, const float* __restrict__ Wk,
    const float* __restrict__ Wv, _Float16* __restrict__ Wh)
{
  int i = (blockIdx.x * 256 + threadIdx.x) * 8;
  const float* src = (i < 131072) ? Wq : ((i < 262144) ? Wk : Wv);
  int off = i & 131071;
  f32x4 a = *(const f32x4*)(src + off);
  f32x4 b = *(const f32x4*)(src + off + 4);
  f16x8 h;
  #pragma unroll
  for (int j = 0; j < 4; ++j) { h[j] = (_Float16)a[j]; h[j + 4] = (_Float16)b[j]; }
  *(f16x8*)(Wh + i) = h;
}

// ---------------------------------------------------------------------------
// Projections. A (x) staged f32 with cvt-at-fragment (r12-proven path);
// B (W) staged f16 from Wh -> half the staged bytes, no B-side cvt, B frag =
// one ds_read_b128. B LDS layout: granule d = rowhi*16 + slot, slot =
// (((row&3)<<2)|g) ^ (rowhi&15)  (4-bit XOR -> 0-conflict reads, attn-style).
// 64x128 tile, grid 256x3 = 768 blocks, BK=32, dbuf 32 KB.
// ---------------------------------------------------------------------------
__global__ __launch_bounds__(256) void gemm_qkv(
    const float* __restrict__ x, const _Float16* __restrict__ Wh,
    _Float16* __restrict__ qk, _Float16* __restrict__ vt)
{
  __shared__ char smem[32768];          // A0 0..8K | B0 8..16K | A1 16..24K | B1 24..32K
  char* Ab[2] = { smem,        smem + 16384 };
  char* Bb[2] = { smem + 8192, smem + 24576 };
  const int tid  = threadIdx.x;
  const int lane = tid & 63, wid = tid >> 6;
  const int g = lane >> 4, l15 = lane & 15;
  const int m0 = blockIdx.x * 64;
  const int by = blockIdx.y;

  // A: 64x32 f32 = 512 granules (2/thread), source XOR ^(row&7) (r12-proven)
  const char* pA[2];
  #pragma unroll
  for (int it = 0; it < 2; ++it) {
    int G = it * 256 + tid, row = G >> 3, gg = (G & 7) ^ (row & 7);
    pA[it] = (const char*)x + (size_t)(m0 + row) * 4096 + gg * 16;
  }
  // B: 128x32 f16 = 512 granules (2/thread), 4-bit XOR layout (see header)
  const char* pB[2];
  #pragma unroll
  for (int it = 0; it < 2; ++it) {
    int d = it * 256 + tid;
    int rowhi = d >> 4, tt = (d & 15) ^ (rowhi & 15);
    int row = rowhi * 4 + (tt >> 2), gg = tt & 3;
    pB[it] = (const char*)(Wh + (size_t)by * 131072 + (size_t)row * 1024) + gg * 16;
  }

#define GSTAGE(bi) do {                                                        \
    _Pragma("unroll")                                                          \
    for (int it_ = 0; it_ < 2; ++it_) {                                        \
      __builtin_amdgcn_global_load_lds(pA[it_],                                \
          Ab[bi] + it_ * 4096 + wid * 1024, 16, 0, 0);                         \
      pA[it_] += 128;                                                          \
      __builtin_amdgcn_global_load_lds(pB[it_],                                \
          Bb[bi] + it_ * 4096 + wid * 1024, 16, 0, 0);                         \
      pB[it_] += 64;                                                           \
    }                                                                          \
  } while (0)

  f32x4 acc[4][2] = {};

#define GCOMPUTE(bi) do {                                                      \
    f16x8 af[4], bg[2];                                                        \
    _Pragma("unroll")                                                          \
    for (int mt = 0; mt < 4; ++mt) {                                           \
      int row = mt * 16 + l15;                                                 \
      const char* base = Ab[bi] + row * 128;                                   \
      f32x4 a0 = *(const f32x4*)(base + (((2 * g    ) ^ (row & 7)) << 4));     \
      f32x4 a1 = *(const f32x4*)(base + (((2 * g + 1) ^ (row & 7)) << 4));     \
      _Pragma("unroll")                                                        \
      for (int i = 0; i < 4; ++i) {                                            \
        af[mt][i] = (_Float16)a0[i]; af[mt][i + 4] = (_Float16)a1[i];          \
      }                                                                        \
    }                                                                          \
    _Pragma("unroll")                                                          \
    for (int nt = 0; nt < 2; ++nt) {                                           \
      int row = wid * 32 + nt * 16 + l15;                                      \
      int byte = ((row >> 2) * 256) +                                          \
                 (((((row & 3) << 2) | g) ^ ((row >> 2) & 15)) << 4);          \
      bg[nt] = *(const f16x8*)(Bb[bi] + byte);                                 \
    }                                                                          \
    __builtin_amdgcn_s_setprio(1);                                             \
    _Pragma("unroll")                                                          \
    for (int mt = 0; mt < 4; ++mt)                                             \
      _Pragma("unroll")                                                        \
      for (int nt = 0; nt < 2; ++nt)                                           \
        acc[mt][nt] = __builtin_amdgcn_mfma_f32_16x16x32_f16(af[mt], bg[nt],   \
                                                             acc[mt][nt], 0, 0, 0); \
    __builtin_amdgcn_s_setprio(0);                                             \
  } while (0)

  GSTAGE(0);
  __syncthreads();
  for (int t = 0; t < 32; t += 2) {
    GSTAGE(1);
    GCOMPUTE(0);
    __syncthreads();
    if (t + 2 < 32) GSTAGE(0);
    GCOMPUTE(1);
    __syncthreads();
  }

  if (by < 2) {
    // D layout (m89): col = l15, row = 4g + r
    #pragma unroll
    for (int mt = 0; mt < 4; ++mt)
      #pragma unroll
      for (int nt = 0; nt < 2; ++nt)
        #pragma unroll
        for (int r = 0; r < 4; ++r) {
          int row = m0 + mt * 16 + (g << 2) + r;
          int col = by * 128 + wid * 32 + nt * 16 + l15;
          qk[(size_t)row * 256 + col] = (_Float16)acc[mt][nt][r];
        }
  } else {
    // V: transpose 64(s) x 128(f) through LDS, then granule-permuted stores
    _Float16* T = (_Float16*)smem;      // [64 s][128 f] = 16 KB (tiles dead)
    #pragma unroll
    for (int mt = 0; mt < 4; ++mt)
      #pragma unroll
      for (int nt = 0; nt < 2; ++nt)
        #pragma unroll
        for (int r = 0; r < 4; ++r)
          T[(mt * 16 + (g << 2) + r) * 128 + wid * 32 + nt * 16 + l15] =
              (_Float16)acc[mt][nt][r];
    __syncthreads();
    const int b = m0 >> 12, s_base = m0 & 4095;
    #pragma unroll
    for (int it = 0; it < 4; ++it) {
      int Wn = it * 256 + tid;           // 0..1023
      int f = Wn >> 3, gran = Wn & 7;
      int kk = gran >> 2, q = gran & 3;
      f16x8 v;
      #pragma unroll
      for (int i = 0; i < 8; ++i) {
        int h = i >> 2, j = i & 3;
        v[i] = T[(kk * 32 + h * 16 + q * 4 + j) * 128 + f];
      }
      *(f16x8*)((char*)vt + (size_t)(b * 128 + f) * 8192 + s_base * 2 + gran * 16) = v;
    }
  }
#undef GSTAGE
#undef GCOMPUTE
}

// ---------------------------------------------------------------------------
// Flash attention (r8/r12-proven, unchanged). KV-split, 8 waves x 16 q-rows,
// double-buffered K/V, swapped QK^T, permuted-V single-b128 fragments,
// defer-max. Emits NORMALIZED O (f16) + (m,l).
// ---------------------------------------------------------------------------
__global__ __launch_bounds__(512, 4) void attn(const _Float16* __restrict__ qk,
                                               const _Float16* __restrict__ vt,
                                               _Float16* __restrict__ pO,
                                               float* __restrict__ pml,
                                               int ntiles)
{
  __shared__ _Float16 K0l[64 * 128], K1l[64 * 128];
  __shared__ _Float16 V0l[64 * 128], V1l[64 * 128];
  const int tid  = threadIdx.x;
  const int lane = tid & 63, wid = tid >> 6;
  const int g = lane >> 4, l15 = lane & 15;
  const int b  = blockIdx.y;
  const int q0 = blockIdx.x * 128;
  const int split = blockIdx.z;
  const int kv_begin = split * (ntiles * 64);

  f16x8 qf[4];
  {
    const size_t qrow = (size_t)(b * S_ + q0 + wid * 16 + l15) * 256;
    #pragma unroll
    for (int kk = 0; kk < 4; ++kk)
      qf[kk] = *(const f16x8*)(qk + qrow + kk * 32 + g * 8);
  }

  const char* gK[2]; const char* gV[2];
  #pragma unroll
  for (int it = 0; it < 2; ++it) {
    int G = it * 512 + tid;
    int row = G >> 4, ch = G & 15;
    gK[it] = (const char*)qk + (size_t)(b * S_ + kv_begin + row) * 512 + 256 +
             (((ch << 4)) ^ ((row & 15) << 4));
    int f = G >> 3, c = G & 7;
    gV[it] = (const char*)vt + (size_t)(b * 128 + f) * 8192 + (kv_begin >> 6) * 128 +
             ((c ^ (f & 7)) << 4);
  }

#define STAGE(Kb, Vb) do {                                                          \
    _Pragma("unroll")                                                               \
    for (int it_ = 0; it_ < 2; ++it_) {                                             \
      __builtin_amdgcn_global_load_lds(gK[it_],                                     \
          (char*)(Kb) + (it_ * 512 + wid * 64) * 16, 16, 0, 0);                     \
      __builtin_amdgcn_global_load_lds(gV[it_],                                     \
          (char*)(Vb) + (it_ * 512 + wid * 64) * 16, 16, 0, 0);                     \
    }                                                                               \
    gK[0] += 32768; gK[1] += 32768; gV[0] += 128; gV[1] += 128;                     \
  } while (0)

  f32x4 oacc[8] = {};
  float m_run = -1e30f, l_run = 0.f;

#define COMPUTE(Kb, Vb) do {                                                        \
    f32x4 sacc[4] = {};                                                             \
    __builtin_amdgcn_s_setprio(1);                                                  \
    _Pragma("unroll")                                                               \
    for (int kk = 0; kk < 4; ++kk) {                                                \
      const char* kb = (const char*)(Kb) + l15 * 256 +                              \
                       (((kk << 6) | (g << 4)) ^ (l15 << 4));                       \
      _Pragma("unroll")                                                             \
      for (int kvt = 0; kvt < 4; ++kvt) {                                           \
        f16x8 kf = *(const f16x8*)(kb + kvt * 4096);                                \
        sacc[kvt] = __builtin_amdgcn_mfma_f32_16x16x32_f16(kf, qf[kk], sacc[kvt],   \
                                                           0, 0, 0);                \
      }                                                                             \
    }                                                                               \
    __builtin_amdgcn_s_setprio(0);                                                  \
    float pmax = -1e30f;                                                            \
    _Pragma("unroll")                                                               \
    for (int kvt = 0; kvt < 4; ++kvt)                                               \
      _Pragma("unroll")                                                             \
      for (int r = 0; r < 4; ++r) {                                                 \
        float s = sacc[kvt][r] * 0.03125f;                                          \
        sacc[kvt][r] = s;                                                           \
        pmax = fmaxf(pmax, s);                                                      \
      }                                                                             \
    pmax = fmaxf(pmax, __shfl_xor(pmax, 16));                                       \
    pmax = fmaxf(pmax, __shfl_xor(pmax, 32));                                       \
    if (!__all(pmax - m_run <= 5.5f)) {                                             \
      float m_new = fmaxf(m_run, pmax);                                             \
      float corr  = __expf(m_run - m_new);                                          \
      l_run *= corr;                                                                \
      m_run  = m_new;                                                               \
      _Pragma("unroll")                                                             \
      for (int r = 0; r < 4; ++r) {                                                 \
        float cr = __builtin_bit_cast(float,                                        \
            __builtin_amdgcn_ds_bpermute((((g << 2) + r) << 2),                     \
                                         __builtin_bit_cast(int, corr)));           \
        _Pragma("unroll")                                                           \
        for (int ft = 0; ft < 8; ++ft) oacc[ft][r] *= cr;                           \
      }                                                                             \
    }                                                                               \
    float psum = 0.f;                                                               \
    f16x8 pa[2];                                                                    \
    _Pragma("unroll")                                                               \
    for (int k2 = 0; k2 < 2; ++k2)                                                  \
      _Pragma("unroll")                                                             \
      for (int i = 0; i < 8; ++i) {                                                 \
        float p = __expf(sacc[2 * k2 + (i >> 2)][i & 3] - m_run);                   \
        psum += p;                                                                  \
        pa[k2][i] = (_Float16)p;                                                    \
      }                                                                             \
    psum += __shfl_xor(psum, 16);                                                   \
    psum += __shfl_xor(psum, 32);                                                   \
    l_run += psum;                                                                  \
    __builtin_amdgcn_s_setprio(1);                                                  \
    _Pragma("unroll")                                                               \
    for (int k2 = 0; k2 < 2; ++k2) {                                                \
      const char* vb = (const char*)(Vb) + l15 * 128 +                              \
                       (((k2 << 6) | (g << 4)) ^ ((l15 & 7) << 4));                 \
      _Pragma("unroll")                                                             \
      for (int ft = 0; ft < 8; ++ft) {                                              \
        f16x8 vf = *(const f16x8*)(vb + ft * 2048);                                 \
        oacc[ft] = __builtin_amdgcn_mfma_f32_16x16x32_f16(pa[k2], vf, oacc[ft],     \
                                                          0, 0, 0);                 \
      }                                                                             \
    }                                                                               \
    __builtin_amdgcn_s_setprio(0);                                                  \
  } while (0)

  STAGE(K0l, V0l);
  __syncthreads();
  for (int t = 0; t < ntiles; t += 2) {
    STAGE(K1l, V1l);
    COMPUTE(K0l, V0l);
    __syncthreads();
    if (t + 2 < ntiles) STAGE(K0l, V0l);
    COMPUTE(K1l, V1l);
    __syncthreads();
  }

  #pragma unroll
  for (int r = 0; r < 4; ++r) {
    float mr = __builtin_bit_cast(float,
                 __builtin_amdgcn_ds_bpermute((((g << 2) + r) << 2),
                                              __builtin_bit_cast(int, m_run)));
    float lr = __builtin_bit_cast(float,
                 __builtin_amdgcn_ds_bpermute((((g << 2) + r) << 2),
                                              __builtin_bit_cast(int, l_run)));
    float inv = 1.f / lr;
    const int grow = b * S_ + q0 + wid * 16 + (g << 2) + r;
    _Float16* od = pO + ((size_t)split * NROWS + grow) * 128;
    #pragma unroll
    for (int ft = 0; ft < 8; ++ft)
      od[ft * 16 + l15] = (_Float16)(oacc[ft][r] * inv);
    if (l15 == 0)
      *(f32x2*)(pml + ((size_t)split * NROWS + grow) * 2) = f32x2{mr, lr};
  }
#undef STAGE
#undef COMPUTE
}

// ---------------------------------------------------------------------------
// Combine: out = sum_s w_s l_s O'_s / sum_s w_s l_s,  w_s = exp(m_s - M)
// ---------------------------------------------------------------------------
__global__ __launch_bounds__(256) void combine(const _Float16* __restrict__ pO,
                                               const float* __restrict__ pml,
                                               float* __restrict__ out,
                                               int nsplit)
{
  const int tid = threadIdx.x;
  const int row = blockIdx.x * 2 + (tid >> 7);
  const int col = tid & 127;

  float M = -1e30f;
  for (int s = 0; s < nsplit; ++s)
    M = fmaxf(M, pml[((size_t)s * NROWS + row) * 2]);
  float den = 0.f, num = 0.f;
  for (int s = 0; s < nsplit; ++s) {
    f32x2 ml = *(const f32x2*)(pml + ((size_t)s * NROWS + row) * 2);
    float w = __expf(ml.x - M) * ml.y;
    den += w;
    num += w * (float)pO[((size_t)s * NROWS + row) * 128 + col];
  }
  out[(size_t)row * 128 + col] = num / den;
}

extern "C" void kernel_launch(void* const* d_in, const int* in_sizes, int n_in,
                              void* d_out, int out_size, void* d_ws, size_t ws_size,
                              hipStream_t stream)
{
  (void)in_sizes; (void)n_in; (void)out_size;
  const float* x  = (const float*)d_in[0];
  const float* Wq = (const float*)d_in[1];
  const float* Wk = (const float*)d_in[2];
  const float* Wv = (const float*)d_in[3];

  char* ws = (char*)d_ws;
  _Float16* qkbuf = (_Float16*)ws;                               // 8.39 MB
  _Float16* vtbuf = (_Float16*)(ws + (size_t)NROWS * 256 * 2);   // 4.19 MB
  const size_t base  = (size_t)NROWS * 256 * 2 + (size_t)4 * 128 * 4096 * 2;
  const size_t perO  = (size_t)NROWS * 128 * 2;                  // 4.19 MB / split (f16)
  const size_t perML = (size_t)NROWS * 2 * 4;                    // 128 KB / split

  int nsplit = 4;
  while (nsplit > 1 && base + (size_t)nsplit * (perO + perML) > ws_size) nsplit >>= 1;

  // Wh (0.79 MB) is TRANSIENT: lives at the start of the pO region; gemm
  // reads it, then attn's pO stores overwrite it (stream-ordered, legal).
  _Float16* Whb = (_Float16*)(ws + base);
  _Float16* pO  = (_Float16*)(ws + base);
  float*    pml = (float*)(ws + base + (size_t)nsplit * perO);
  float*    out = (float*)d_out;

  cvtw<<<192, 256, 0, stream>>>(Wq, Wk, Wv, Whb);
  dim3 gg(256, 3);
  gemm_qkv<<<gg, 256, 0, stream>>>(x, Whb, qkbuf, vtbuf);
  dim3 ga(S_ / 128, 4, nsplit);
  attn<<<ga, 512, 0, stream>>>(qkbuf, vtbuf, pO, pml, 64 / nsplit);
  combine<<<NROWS / 2, 256, 0, stream>>>(pO, pml, out, nsplit);
}

// Round 14
// 89.353 us; speedup vs baseline: 1.9282x; 1.0273x over previous
//
#include <hip/hip_runtime.h>
#include <stdint.h>

typedef __attribute__((ext_vector_type(8))) _Float16 f16x8;
typedef __attribute__((ext_vector_type(4))) float f32x4;
typedef __attribute__((ext_vector_type(2))) float f32x2;

#define S_ 4096
#define D_ 1024
#define NROWS 16384          // B*S
#define QSCALE 0.045084220f  // (1/sqrt(1024)) * log2(e): Q pre-scale -> exp2 softmax

// ---------------------------------------------------------------------------
// Tiny pre-pass: Wq|Wk|Wv (3 x 128 x 1024 f32 = 1.5 MB) -> concatenated f16.
// ---------------------------------------------------------------------------
__global__ __launch_bounds__(256) void cvtw(
    const float* __restrict__ Wq, const float* __restrict__ Wk,
    const float* __restrict__ Wv, _Float16* __restrict__ Wh)
{
  int i = (blockIdx.x * 256 + threadIdx.x) * 8;
  const float* src = (i < 131072) ? Wq : ((i < 262144) ? Wk : Wv);
  int off = i & 131071;
  f32x4 a = *(const f32x4*)(src + off);
  f32x4 b = *(const f32x4*)(src + off + 4);
  f16x8 h;
  #pragma unroll
  for (int j = 0; j < 4; ++j) { h[j] = (_Float16)a[j]; h[j + 4] = (_Float16)b[j]; }
  *(f16x8*)(Wh + i) = h;
}

// ---------------------------------------------------------------------------
// Projections (r13-proven). A (x) staged f32 + cvt-at-fragment; B (W) staged
// f16 with 4-bit XOR layout, single ds_read_b128 fragments. Q output is
// pre-scaled by QSCALE (softmax runs in log2 domain downstream).
// ---------------------------------------------------------------------------
__global__ __launch_bounds__(256) void gemm_qkv(
    const float* __restrict__ x, const _Float16* __restrict__ Wh,
    _Float16* __restrict__ qk, _Float16* __restrict__ vt)
{
  __shared__ char smem[32768];          // A0 0..8K | B0 8..16K | A1 16..24K | B1 24..32K
  char* Ab[2] = { smem,        smem + 16384 };
  char* Bb[2] = { smem + 8192, smem + 24576 };
  const int tid  = threadIdx.x;
  const int lane = tid & 63, wid = tid >> 6;
  const int g = lane >> 4, l15 = lane & 15;
  const int m0 = blockIdx.x * 64;
  const int by = blockIdx.y;

  const char* pA[2];
  #pragma unroll
  for (int it = 0; it < 2; ++it) {
    int G = it * 256 + tid, row = G >> 3, gg = (G & 7) ^ (row & 7);
    pA[it] = (const char*)x + (size_t)(m0 + row) * 4096 + gg * 16;
  }
  const char* pB[2];
  #pragma unroll
  for (int it = 0; it < 2; ++it) {
    int d = it * 256 + tid;
    int rowhi = d >> 4, tt = (d & 15) ^ (rowhi & 15);
    int row = rowhi * 4 + (tt >> 2), gg = tt & 3;
    pB[it] = (const char*)(Wh + (size_t)by * 131072 + (size_t)row * 1024) + gg * 16;
  }

#define GSTAGE(bi) do {                                                        \
    _Pragma("unroll")                                                          \
    for (int it_ = 0; it_ < 2; ++it_) {                                        \
      __builtin_amdgcn_global_load_lds(pA[it_],                                \
          Ab[bi] + it_ * 4096 + wid * 1024, 16, 0, 0);                         \
      pA[it_] += 128;                                                          \
      __builtin_amdgcn_global_load_lds(pB[it_],                                \
          Bb[bi] + it_ * 4096 + wid * 1024, 16, 0, 0);                         \
      pB[it_] += 64;                                                           \
    }                                                                          \
  } while (0)

  f32x4 acc[4][2] = {};

#define GCOMPUTE(bi) do {                                                      \
    f16x8 af[4], bg[2];                                                        \
    _Pragma("unroll")                                                          \
    for (int mt = 0; mt < 4; ++mt) {                                           \
      int row = mt * 16 + l15;                                                 \
      const char* base = Ab[bi] + row * 128;                                   \
      f32x4 a0 = *(const f32x4*)(base + (((2 * g    ) ^ (row & 7)) << 4));     \
      f32x4 a1 = *(const f32x4*)(base + (((2 * g + 1) ^ (row & 7)) << 4));     \
      _Pragma("unroll")                                                        \
      for (int i = 0; i < 4; ++i) {                                            \
        af[mt][i] = (_Float16)a0[i]; af[mt][i + 4] = (_Float16)a1[i];          \
      }                                                                        \
    }                                                                          \
    _Pragma("unroll")                                                          \
    for (int nt = 0; nt < 2; ++nt) {                                           \
      int row = wid * 32 + nt * 16 + l15;                                      \
      int byte = ((row >> 2) * 256) +                                          \
                 (((((row & 3) << 2) | g) ^ ((row >> 2) & 15)) << 4);          \
      bg[nt] = *(const f16x8*)(Bb[bi] + byte);                                 \
    }                                                                          \
    __builtin_amdgcn_s_setprio(1);                                             \
    _Pragma("unroll")                                                          \
    for (int mt = 0; mt < 4; ++mt)                                             \
      _Pragma("unroll")                                                        \
      for (int nt = 0; nt < 2; ++nt)                                           \
        acc[mt][nt] = __builtin_amdgcn_mfma_f32_16x16x32_f16(af[mt], bg[nt],   \
                                                             acc[mt][nt], 0, 0, 0); \
    __builtin_amdgcn_s_setprio(0);                                             \
  } while (0)

  GSTAGE(0);
  __syncthreads();
  for (int t = 0; t < 32; t += 2) {
    GSTAGE(1);
    GCOMPUTE(0);
    __syncthreads();
    if (t + 2 < 32) GSTAGE(0);
    GCOMPUTE(1);
    __syncthreads();
  }

  if (by < 2) {
    // D layout (m89): col = l15, row = 4g + r.  Q (by==0) pre-scaled.
    const float sc = (by == 0) ? QSCALE : 1.0f;
    #pragma unroll
    for (int mt = 0; mt < 4; ++mt)
      #pragma unroll
      for (int nt = 0; nt < 2; ++nt)
        #pragma unroll
        for (int r = 0; r < 4; ++r) {
          int row = m0 + mt * 16 + (g << 2) + r;
          int col = by * 128 + wid * 32 + nt * 16 + l15;
          qk[(size_t)row * 256 + col] = (_Float16)(acc[mt][nt][r] * sc);
        }
  } else {
    // V: transpose 64(s) x 128(f) through LDS, then granule-permuted stores
    _Float16* T = (_Float16*)smem;
    #pragma unroll
    for (int mt = 0; mt < 4; ++mt)
      #pragma unroll
      for (int nt = 0; nt < 2; ++nt)
        #pragma unroll
        for (int r = 0; r < 4; ++r)
          T[(mt * 16 + (g << 2) + r) * 128 + wid * 32 + nt * 16 + l15] =
              (_Float16)acc[mt][nt][r];
    __syncthreads();
    const int b = m0 >> 12, s_base = m0 & 4095;
    #pragma unroll
    for (int it = 0; it < 4; ++it) {
      int Wn = it * 256 + tid;
      int f = Wn >> 3, gran = Wn & 7;
      int kk = gran >> 2, q = gran & 3;
      f16x8 v;
      #pragma unroll
      for (int i = 0; i < 8; ++i) {
        int h = i >> 2, j = i & 3;
        v[i] = T[(kk * 32 + h * 16 + q * 4 + j) * 128 + f];
      }
      *(f16x8*)((char*)vt + (size_t)(b * 128 + f) * 8192 + s_base * 2 + gran * 16) = v;
    }
  }
#undef GSTAGE
#undef GCOMPUTE
}

// ---------------------------------------------------------------------------
// Flash attention. Softmax fully in log2 domain (Q pre-scaled): no per-elem
// scale muls, exp2f (1 v_exp), pairwise max tree, defer-max THR=8 (P<=256).
// Structure otherwise r8/r13-proven.
// ---------------------------------------------------------------------------
__global__ __launch_bounds__(512, 4) void attn(const _Float16* __restrict__ qk,
                                               const _Float16* __restrict__ vt,
                                               _Float16* __restrict__ pO,
                                               float* __restrict__ pml,
                                               int ntiles)
{
  __shared__ _Float16 K0l[64 * 128], K1l[64 * 128];
  __shared__ _Float16 V0l[64 * 128], V1l[64 * 128];
  const int tid  = threadIdx.x;
  const int lane = tid & 63, wid = tid >> 6;
  const int g = lane >> 4, l15 = lane & 15;
  const int b  = blockIdx.y;
  const int q0 = blockIdx.x * 128;
  const int split = blockIdx.z;
  const int kv_begin = split * (ntiles * 64);

  f16x8 qf[4];
  {
    const size_t qrow = (size_t)(b * S_ + q0 + wid * 16 + l15) * 256;
    #pragma unroll
    for (int kk = 0; kk < 4; ++kk)
      qf[kk] = *(const f16x8*)(qk + qrow + kk * 32 + g * 8);
  }

  const char* gK[2]; const char* gV[2];
  #pragma unroll
  for (int it = 0; it < 2; ++it) {
    int G = it * 512 + tid;
    int row = G >> 4, ch = G & 15;
    gK[it] = (const char*)qk + (size_t)(b * S_ + kv_begin + row) * 512 + 256 +
             (((ch << 4)) ^ ((row & 15) << 4));
    int f = G >> 3, c = G & 7;
    gV[it] = (const char*)vt + (size_t)(b * 128 + f) * 8192 + (kv_begin >> 6) * 128 +
             ((c ^ (f & 7)) << 4);
  }

#define STAGE(Kb, Vb) do {                                                          \
    _Pragma("unroll")                                                               \
    for (int it_ = 0; it_ < 2; ++it_) {                                             \
      __builtin_amdgcn_global_load_lds(gK[it_],                                     \
          (char*)(Kb) + (it_ * 512 + wid * 64) * 16, 16, 0, 0);                     \
      __builtin_amdgcn_global_load_lds(gV[it_],                                     \
          (char*)(Vb) + (it_ * 512 + wid * 64) * 16, 16, 0, 0);                     \
    }                                                                               \
    gK[0] += 32768; gK[1] += 32768; gV[0] += 128; gV[1] += 128;                     \
  } while (0)

  f32x4 oacc[8] = {};
  float m_run = -1e30f, l_run = 0.f;

#define COMPUTE(Kb, Vb) do {                                                        \
    f32x4 sacc[4] = {};                                                             \
    __builtin_amdgcn_s_setprio(1);                                                  \
    _Pragma("unroll")                                                               \
    for (int kk = 0; kk < 4; ++kk) {                                                \
      const char* kb = (const char*)(Kb) + l15 * 256 +                              \
                       (((kk << 6) | (g << 4)) ^ (l15 << 4));                       \
      _Pragma("unroll")                                                             \
      for (int kvt = 0; kvt < 4; ++kvt) {                                           \
        f16x8 kf = *(const f16x8*)(kb + kvt * 4096);                                \
        sacc[kvt] = __builtin_amdgcn_mfma_f32_16x16x32_f16(kf, qf[kk], sacc[kvt],   \
                                                           0, 0, 0);                \
      }                                                                             \
    }                                                                               \
    __builtin_amdgcn_s_setprio(0);                                                  \
    float x0 = fmaxf(fmaxf(sacc[0][0], sacc[0][1]), fmaxf(sacc[0][2], sacc[0][3])); \
    float x1 = fmaxf(fmaxf(sacc[1][0], sacc[1][1]), fmaxf(sacc[1][2], sacc[1][3])); \
    float x2 = fmaxf(fmaxf(sacc[2][0], sacc[2][1]), fmaxf(sacc[2][2], sacc[2][3])); \
    float x3 = fmaxf(fmaxf(sacc[3][0], sacc[3][1]), fmaxf(sacc[3][2], sacc[3][3])); \
    float pmax = fmaxf(fmaxf(x0, x1), fmaxf(x2, x3));                               \
    pmax = fmaxf(pmax, __shfl_xor(pmax, 16));                                       \
    pmax = fmaxf(pmax, __shfl_xor(pmax, 32));                                       \
    if (!__all(pmax - m_run <= 8.0f)) {                                             \
      float m_new = fmaxf(m_run, pmax);                                             \
      float corr  = exp2f(m_run - m_new);                                           \
      l_run *= corr;                                                                \
      m_run  = m_new;                                                               \
      _Pragma("unroll")                                                             \
      for (int r = 0; r < 4; ++r) {                                                 \
        float cr = __builtin_bit_cast(float,                                        \
            __builtin_amdgcn_ds_bpermute((((g << 2) + r) << 2),                     \
                                         __builtin_bit_cast(int, corr)));           \
        _Pragma("unroll")                                                           \
        for (int ft = 0; ft < 8; ++ft) oacc[ft][r] *= cr;                           \
      }                                                                             \
    }                                                                               \
    float psum = 0.f;                                                               \
    f16x8 pa[2];                                                                    \
    _Pragma("unroll")                                                               \
    for (int k2 = 0; k2 < 2; ++k2)                                                  \
      _Pragma("unroll")                                                             \
      for (int i = 0; i < 8; ++i) {                                                 \
        float p = exp2f(sacc[2 * k2 + (i >> 2)][i & 3] - m_run);                    \
        psum += p;                                                                  \
        pa[k2][i] = (_Float16)p;                                                    \
      }                                                                             \
    psum += __shfl_xor(psum, 16);                                                   \
    psum += __shfl_xor(psum, 32);                                                   \
    l_run += psum;                                                                  \
    __builtin_amdgcn_s_setprio(1);                                                  \
    _Pragma("unroll")                                                               \
    for (int k2 = 0; k2 < 2; ++k2) {                                                \
      const char* vb = (const char*)(Vb) + l15 * 128 +                              \
                       (((k2 << 6) | (g << 4)) ^ ((l15 & 7) << 4));                 \
      _Pragma("unroll")                                                             \
      for (int ft = 0; ft < 8; ++ft) {                                              \
        f16x8 vf = *(const f16x8*)(vb + ft * 2048);                                 \
        oacc[ft] = __builtin_amdgcn_mfma_f32_16x16x32_f16(pa[k2], vf, oacc[ft],     \
                                                          0, 0, 0);                 \
      }                                                                             \
    }                                                                               \
    __builtin_amdgcn_s_setprio(0);                                                  \
  } while (0)

  STAGE(K0l, V0l);
  __syncthreads();
  for (int t = 0; t < ntiles; t += 2) {
    STAGE(K1l, V1l);
    COMPUTE(K0l, V0l);
    __syncthreads();
    if (t + 2 < ntiles) STAGE(K0l, V0l);
    COMPUTE(K1l, V1l);
    __syncthreads();
  }

  #pragma unroll
  for (int r = 0; r < 4; ++r) {
    float mr = __builtin_bit_cast(float,
                 __builtin_amdgcn_ds_bpermute((((g << 2) + r) << 2),
                                              __builtin_bit_cast(int, m_run)));
    float lr = __builtin_bit_cast(float,
                 __builtin_amdgcn_ds_bpermute((((g << 2) + r) << 2),
                                              __builtin_bit_cast(int, l_run)));
    float inv = 1.f / lr;
    const int grow = b * S_ + q0 + wid * 16 + (g << 2) + r;
    _Float16* od = pO + ((size_t)split * NROWS + grow) * 128;
    #pragma unroll
    for (int ft = 0; ft < 8; ++ft)
      od[ft * 16 + l15] = (_Float16)(oacc[ft][r] * inv);
    if (l15 == 0)
      *(f32x2*)(pml + ((size_t)split * NROWS + grow) * 2) = f32x2{mr, lr};
  }
#undef STAGE
#undef COMPUTE
}

// ---------------------------------------------------------------------------
// Combine (vectorized): 16 rows/block, f16x8 reads, f32x4 writes.
// out = sum_s w_s l_s O'_s / sum_s w_s l_s,  w_s = exp2(m_s - M)  (log2 m).
// ---------------------------------------------------------------------------
__global__ __launch_bounds__(256) void combine(const _Float16* __restrict__ pO,
                                               const float* __restrict__ pml,
                                               float* __restrict__ out,
                                               int nsplit)
{
  const int tid  = threadIdx.x;
  const int row  = blockIdx.x * 16 + (tid >> 4);
  const int colg = (tid & 15) * 8;

  float M = -1e30f;
  for (int s = 0; s < nsplit; ++s)
    M = fmaxf(M, pml[((size_t)s * NROWS + row) * 2]);
  float den = 0.f;
  float num[8] = {};
  for (int s = 0; s < nsplit; ++s) {
    f32x2 ml = *(const f32x2*)(pml + ((size_t)s * NROWS + row) * 2);
    float w = exp2f(ml.x - M) * ml.y;
    den += w;
    f16x8 o = *(const f16x8*)(pO + ((size_t)s * NROWS + row) * 128 + colg);
    #pragma unroll
    for (int j = 0; j < 8; ++j) num[j] += w * (float)o[j];
  }
  float inv = 1.f / den;
  f32x4 o0, o1;
  #pragma unroll
  for (int j = 0; j < 4; ++j) { o0[j] = num[j] * inv; o1[j] = num[4 + j] * inv; }
  *(f32x4*)(out + (size_t)row * 128 + colg)     = o0;
  *(f32x4*)(out + (size_t)row * 128 + colg + 4) = o1;
}

extern "C" void kernel_launch(void* const* d_in, const int* in_sizes, int n_in,
                              void* d_out, int out_size, void* d_ws, size_t ws_size,
                              hipStream_t stream)
{
  (void)in_sizes; (void)n_in; (void)out_size;
  const float* x  = (const float*)d_in[0];
  const float* Wq = (const float*)d_in[1];
  const float* Wk = (const float*)d_in[2];
  const float* Wv = (const float*)d_in[3];

  char* ws = (char*)d_ws;
  _Float16* qkbuf = (_Float16*)ws;                               // 8.39 MB
  _Float16* vtbuf = (_Float16*)(ws + (size_t)NROWS * 256 * 2);   // 4.19 MB
  const size_t base  = (size_t)NROWS * 256 * 2 + (size_t)4 * 128 * 4096 * 2;
  const size_t perO  = (size_t)NROWS * 128 * 2;                  // 4.19 MB / split (f16)
  const size_t perML = (size_t)NROWS * 2 * 4;                    // 128 KB / split

  int nsplit = 4;
  while (nsplit > 1 && base + (size_t)nsplit * (perO + perML) > ws_size) nsplit >>= 1;

  // Wh (0.79 MB) transient at start of pO region (gemm reads, attn overwrites)
  _Float16* Whb = (_Float16*)(ws + base);
  _Float16* pO  = (_Float16*)(ws + base);
  float*    pml = (float*)(ws + base + (size_t)nsplit * perO);
  float*    out = (float*)d_out;

  cvtw<<<192, 256, 0, stream>>>(Wq, Wk, Wv, Whb);
  dim3 gg(256, 3);
  gemm_qkv<<<gg, 256, 0, stream>>>(x, Whb, qkbuf, vtbuf);
  dim3 ga(S_ / 128, 4, nsplit);
  attn<<<ga, 512, 0, stream>>>(qkbuf, vtbuf, pO, pml, 64 / nsplit);
  combine<<<NROWS / 16, 256, 0, stream>>>(pO, pml, out, nsplit);
}

// Round 15
// 83.822 us; speedup vs baseline: 2.0554x; 1.0660x over previous
//
#include <hip/hip_runtime.h>
#include <stdint.h>

typedef __attribute__((ext_vector_type(8))) _Float16 f16x8;
typedef __attribute__((ext_vector_type(4))) float f32x4;
typedef __attribute__((ext_vector_type(2))) float f32x2;

#define S_ 4096
#define D_ 1024
#define NROWS 16384          // B*S
#define QSCALE 0.045084220f  // (1/sqrt(1024)) * log2(e): Q pre-scale -> exp2 softmax
#define EXP2(x) __builtin_amdgcn_exp2f(x)   // raw v_exp_f32 (2^x), NOT libm exp2f

// ---------------------------------------------------------------------------
// Tiny pre-pass: Wq|Wk|Wv (3 x 128 x 1024 f32 = 1.5 MB) -> concatenated f16.
// ---------------------------------------------------------------------------
__global__ __launch_bounds__(256) void cvtw(
    const float* __restrict__ Wq, const float* __restrict__ Wk,
    const float* __restrict__ Wv, _Float16* __restrict__ Wh)
{
  int i = (blockIdx.x * 256 + threadIdx.x) * 8;
  const float* src = (i < 131072) ? Wq : ((i < 262144) ? Wk : Wv);
  int off = i & 131071;
  f32x4 a = *(const f32x4*)(src + off);
  f32x4 b = *(const f32x4*)(src + off + 4);
  f16x8 h;
  #pragma unroll
  for (int j = 0; j < 4; ++j) { h[j] = (_Float16)a[j]; h[j + 4] = (_Float16)b[j]; }
  *(f16x8*)(Wh + i) = h;
}

// ---------------------------------------------------------------------------
// Projections (r13-proven). A (x) staged f32 + cvt-at-fragment; B (W) staged
// f16 with 4-bit XOR layout, single ds_read_b128 fragments. Q output is
// pre-scaled by QSCALE (softmax runs in log2 domain downstream).
// ---------------------------------------------------------------------------
__global__ __launch_bounds__(256) void gemm_qkv(
    const float* __restrict__ x, const _Float16* __restrict__ Wh,
    _Float16* __restrict__ qk, _Float16* __restrict__ vt)
{
  __shared__ char smem[32768];          // A0 0..8K | B0 8..16K | A1 16..24K | B1 24..32K
  char* Ab[2] = { smem,        smem + 16384 };
  char* Bb[2] = { smem + 8192, smem + 24576 };
  const int tid  = threadIdx.x;
  const int lane = tid & 63, wid = tid >> 6;
  const int g = lane >> 4, l15 = lane & 15;
  const int m0 = blockIdx.x * 64;
  const int by = blockIdx.y;

  const char* pA[2];
  #pragma unroll
  for (int it = 0; it < 2; ++it) {
    int G = it * 256 + tid, row = G >> 3, gg = (G & 7) ^ (row & 7);
    pA[it] = (const char*)x + (size_t)(m0 + row) * 4096 + gg * 16;
  }
  const char* pB[2];
  #pragma unroll
  for (int it = 0; it < 2; ++it) {
    int d = it * 256 + tid;
    int rowhi = d >> 4, tt = (d & 15) ^ (rowhi & 15);
    int row = rowhi * 4 + (tt >> 2), gg = tt & 3;
    pB[it] = (const char*)(Wh + (size_t)by * 131072 + (size_t)row * 1024) + gg * 16;
  }

#define GSTAGE(bi) do {                                                        \
    _Pragma("unroll")                                                          \
    for (int it_ = 0; it_ < 2; ++it_) {                                        \
      __builtin_amdgcn_global_load_lds(pA[it_],                                \
          Ab[bi] + it_ * 4096 + wid * 1024, 16, 0, 0);                         \
      pA[it_] += 128;                                                          \
      __builtin_amdgcn_global_load_lds(pB[it_],                                \
          Bb[bi] + it_ * 4096 + wid * 1024, 16, 0, 0);                         \
      pB[it_] += 64;                                                           \
    }                                                                          \
  } while (0)

  f32x4 acc[4][2] = {};

#define GCOMPUTE(bi) do {                                                      \
    f16x8 af[4], bg[2];                                                        \
    _Pragma("unroll")                                                          \
    for (int mt = 0; mt < 4; ++mt) {                                           \
      int row = mt * 16 + l15;                                                 \
      const char* base = Ab[bi] + row * 128;                                   \
      f32x4 a0 = *(const f32x4*)(base + (((2 * g    ) ^ (row & 7)) << 4));     \
      f32x4 a1 = *(const f32x4*)(base + (((2 * g + 1) ^ (row & 7)) << 4));     \
      _Pragma("unroll")                                                        \
      for (int i = 0; i < 4; ++i) {                                            \
        af[mt][i] = (_Float16)a0[i]; af[mt][i + 4] = (_Float16)a1[i];          \
      }                                                                        \
    }                                                                          \
    _Pragma("unroll")                                                          \
    for (int nt = 0; nt < 2; ++nt) {                                           \
      int row = wid * 32 + nt * 16 + l15;                                      \
      int byte = ((row >> 2) * 256) +                                          \
                 (((((row & 3) << 2) | g) ^ ((row >> 2) & 15)) << 4);          \
      bg[nt] = *(const f16x8*)(Bb[bi] + byte);                                 \
    }                                                                          \
    __builtin_amdgcn_s_setprio(1);                                             \
    _Pragma("unroll")                                                          \
    for (int mt = 0; mt < 4; ++mt)                                             \
      _Pragma("unroll")                                                        \
      for (int nt = 0; nt < 2; ++nt)                                           \
        acc[mt][nt] = __builtin_amdgcn_mfma_f32_16x16x32_f16(af[mt], bg[nt],   \
                                                             acc[mt][nt], 0, 0, 0); \
    __builtin_amdgcn_s_setprio(0);                                             \
  } while (0)

  GSTAGE(0);
  __syncthreads();
  for (int t = 0; t < 32; t += 2) {
    GSTAGE(1);
    GCOMPUTE(0);
    __syncthreads();
    if (t + 2 < 32) GSTAGE(0);
    GCOMPUTE(1);
    __syncthreads();
  }

  if (by < 2) {
    // D layout (m89): col = l15, row = 4g + r.  Q (by==0) pre-scaled.
    const float sc = (by == 0) ? QSCALE : 1.0f;
    #pragma unroll
    for (int mt = 0; mt < 4; ++mt)
      #pragma unroll
      for (int nt = 0; nt < 2; ++nt)
        #pragma unroll
        for (int r = 0; r < 4; ++r) {
          int row = m0 + mt * 16 + (g << 2) + r;
          int col = by * 128 + wid * 32 + nt * 16 + l15;
          qk[(size_t)row * 256 + col] = (_Float16)(acc[mt][nt][r] * sc);
        }
  } else {
    // V: transpose 64(s) x 128(f) through LDS, then granule-permuted stores
    _Float16* T = (_Float16*)smem;
    #pragma unroll
    for (int mt = 0; mt < 4; ++mt)
      #pragma unroll
      for (int nt = 0; nt < 2; ++nt)
        #pragma unroll
        for (int r = 0; r < 4; ++r)
          T[(mt * 16 + (g << 2) + r) * 128 + wid * 32 + nt * 16 + l15] =
              (_Float16)acc[mt][nt][r];
    __syncthreads();
    const int b = m0 >> 12, s_base = m0 & 4095;
    #pragma unroll
    for (int it = 0; it < 4; ++it) {
      int Wn = it * 256 + tid;
      int f = Wn >> 3, gran = Wn & 7;
      int kk = gran >> 2, q = gran & 3;
      f16x8 v;
      #pragma unroll
      for (int i = 0; i < 8; ++i) {
        int h = i >> 2, j = i & 3;
        v[i] = T[(kk * 32 + h * 16 + q * 4 + j) * 128 + f];
      }
      *(f16x8*)((char*)vt + (size_t)(b * 128 + f) * 8192 + s_base * 2 + gran * 16) = v;
    }
  }
#undef GSTAGE
#undef GCOMPUTE
}

// ---------------------------------------------------------------------------
// Flash attention. Log2-domain softmax with RAW v_exp_f32 (EXP2 builtin --
// r14's libm exp2f was the regression), pairwise max tree, defer-max THR=8.
// Structure otherwise r8/r13-proven.
// ---------------------------------------------------------------------------
__global__ __launch_bounds__(512, 4) void attn(const _Float16* __restrict__ qk,
                                               const _Float16* __restrict__ vt,
                                               _Float16* __restrict__ pO,
                                               float* __restrict__ pml,
                                               int ntiles)
{
  __shared__ _Float16 K0l[64 * 128], K1l[64 * 128];
  __shared__ _Float16 V0l[64 * 128], V1l[64 * 128];
  const int tid  = threadIdx.x;
  const int lane = tid & 63, wid = tid >> 6;
  const int g = lane >> 4, l15 = lane & 15;
  const int b  = blockIdx.y;
  const int q0 = blockIdx.x * 128;
  const int split = blockIdx.z;
  const int kv_begin = split * (ntiles * 64);

  f16x8 qf[4];
  {
    const size_t qrow = (size_t)(b * S_ + q0 + wid * 16 + l15) * 256;
    #pragma unroll
    for (int kk = 0; kk < 4; ++kk)
      qf[kk] = *(const f16x8*)(qk + qrow + kk * 32 + g * 8);
  }

  const char* gK[2]; const char* gV[2];
  #pragma unroll
  for (int it = 0; it < 2; ++it) {
    int G = it * 512 + tid;
    int row = G >> 4, ch = G & 15;
    gK[it] = (const char*)qk + (size_t)(b * S_ + kv_begin + row) * 512 + 256 +
             (((ch << 4)) ^ ((row & 15) << 4));
    int f = G >> 3, c = G & 7;
    gV[it] = (const char*)vt + (size_t)(b * 128 + f) * 8192 + (kv_begin >> 6) * 128 +
             ((c ^ (f & 7)) << 4);
  }

#define STAGE(Kb, Vb) do {                                                          \
    _Pragma("unroll")                                                               \
    for (int it_ = 0; it_ < 2; ++it_) {                                             \
      __builtin_amdgcn_global_load_lds(gK[it_],                                     \
          (char*)(Kb) + (it_ * 512 + wid * 64) * 16, 16, 0, 0);                     \
      __builtin_amdgcn_global_load_lds(gV[it_],                                     \
          (char*)(Vb) + (it_ * 512 + wid * 64) * 16, 16, 0, 0);                     \
    }                                                                               \
    gK[0] += 32768; gK[1] += 32768; gV[0] += 128; gV[1] += 128;                     \
  } while (0)

  f32x4 oacc[8] = {};
  float m_run = -1e30f, l_run = 0.f;

#define COMPUTE(Kb, Vb) do {                                                        \
    f32x4 sacc[4] = {};                                                             \
    __builtin_amdgcn_s_setprio(1);                                                  \
    _Pragma("unroll")                                                               \
    for (int kk = 0; kk < 4; ++kk) {                                                \
      const char* kb = (const char*)(Kb) + l15 * 256 +                              \
                       (((kk << 6) | (g << 4)) ^ (l15 << 4));                       \
      _Pragma("unroll")                                                             \
      for (int kvt = 0; kvt < 4; ++kvt) {                                           \
        f16x8 kf = *(const f16x8*)(kb + kvt * 4096);                                \
        sacc[kvt] = __builtin_amdgcn_mfma_f32_16x16x32_f16(kf, qf[kk], sacc[kvt],   \
                                                           0, 0, 0);                \
      }                                                                             \
    }                                                                               \
    __builtin_amdgcn_s_setprio(0);                                                  \
    float x0 = fmaxf(fmaxf(sacc[0][0], sacc[0][1]), fmaxf(sacc[0][2], sacc[0][3])); \
    float x1 = fmaxf(fmaxf(sacc[1][0], sacc[1][1]), fmaxf(sacc[1][2], sacc[1][3])); \
    float x2 = fmaxf(fmaxf(sacc[2][0], sacc[2][1]), fmaxf(sacc[2][2], sacc[2][3])); \
    float x3 = fmaxf(fmaxf(sacc[3][0], sacc[3][1]), fmaxf(sacc[3][2], sacc[3][3])); \
    float pmax = fmaxf(fmaxf(x0, x1), fmaxf(x2, x3));                               \
    pmax = fmaxf(pmax, __shfl_xor(pmax, 16));                                       \
    pmax = fmaxf(pmax, __shfl_xor(pmax, 32));                                       \
    if (!__all(pmax - m_run <= 8.0f)) {                                             \
      float m_new = fmaxf(m_run, pmax);                                             \
      float corr  = EXP2(m_run - m_new);                                            \
      l_run *= corr;                                                                \
      m_run  = m_new;                                                               \
      _Pragma("unroll")                                                             \
      for (int r = 0; r < 4; ++r) {                                                 \
        float cr = __builtin_bit_cast(float,                                        \
            __builtin_amdgcn_ds_bpermute((((g << 2) + r) << 2),                     \
                                         __builtin_bit_cast(int, corr)));           \
        _Pragma("unroll")                                                           \
        for (int ft = 0; ft < 8; ++ft) oacc[ft][r] *= cr;                           \
      }                                                                             \
    }                                                                               \
    float psum = 0.f;                                                               \
    f16x8 pa[2];                                                                    \
    _Pragma("unroll")                                                               \
    for (int k2 = 0; k2 < 2; ++k2)                                                  \
      _Pragma("unroll")                                                             \
      for (int i = 0; i < 8; ++i) {                                                 \
        float p = EXP2(sacc[2 * k2 + (i >> 2)][i & 3] - m_run);                     \
        psum += p;                                                                  \
        pa[k2][i] = (_Float16)p;                                                    \
      }                                                                             \
    psum += __shfl_xor(psum, 16);                                                   \
    psum += __shfl_xor(psum, 32);                                                   \
    l_run += psum;                                                                  \
    __builtin_amdgcn_s_setprio(1);                                                  \
    _Pragma("unroll")                                                               \
    for (int k2 = 0; k2 < 2; ++k2) {                                                \
      const char* vb = (const char*)(Vb) + l15 * 128 +                              \
                       (((k2 << 6) | (g << 4)) ^ ((l15 & 7) << 4));                 \
      _Pragma("unroll")                                                             \
      for (int ft = 0; ft < 8; ++ft) {                                              \
        f16x8 vf = *(const f16x8*)(vb + ft * 2048);                                 \
        oacc[ft] = __builtin_amdgcn_mfma_f32_16x16x32_f16(pa[k2], vf, oacc[ft],     \
                                                          0, 0, 0);                 \
      }                                                                             \
    }                                                                               \
    __builtin_amdgcn_s_setprio(0);                                                  \
  } while (0)

  STAGE(K0l, V0l);
  __syncthreads();
  for (int t = 0; t < ntiles; t += 2) {
    STAGE(K1l, V1l);
    COMPUTE(K0l, V0l);
    __syncthreads();
    if (t + 2 < ntiles) STAGE(K0l, V0l);
    COMPUTE(K1l, V1l);
    __syncthreads();
  }

  #pragma unroll
  for (int r = 0; r < 4; ++r) {
    float mr = __builtin_bit_cast(float,
                 __builtin_amdgcn_ds_bpermute((((g << 2) + r) << 2),
                                              __builtin_bit_cast(int, m_run)));
    float lr = __builtin_bit_cast(float,
                 __builtin_amdgcn_ds_bpermute((((g << 2) + r) << 2),
                                              __builtin_bit_cast(int, l_run)));
    float inv = 1.f / lr;
    const int grow = b * S_ + q0 + wid * 16 + (g << 2) + r;
    _Float16* od = pO + ((size_t)split * NROWS + grow) * 128;
    #pragma unroll
    for (int ft = 0; ft < 8; ++ft)
      od[ft * 16 + l15] = (_Float16)(oacc[ft][r] * inv);
    if (l15 == 0)
      *(f32x2*)(pml + ((size_t)split * NROWS + grow) * 2) = f32x2{mr, lr};
  }
#undef STAGE
#undef COMPUTE
}

// ---------------------------------------------------------------------------
// Combine (vectorized): 16 rows/block, f16x8 reads, f32x4 writes.
// out = sum_s w_s l_s O'_s / sum_s w_s l_s,  w_s = exp2(m_s - M)  (log2 m).
// ---------------------------------------------------------------------------
__global__ __launch_bounds__(256) void combine(const _Float16* __restrict__ pO,
                                               const float* __restrict__ pml,
                                               float* __restrict__ out,
                                               int nsplit)
{
  const int tid  = threadIdx.x;
  const int row  = blockIdx.x * 16 + (tid >> 4);
  const int colg = (tid & 15) * 8;

  float M = -1e30f;
  for (int s = 0; s < nsplit; ++s)
    M = fmaxf(M, pml[((size_t)s * NROWS + row) * 2]);
  float den = 0.f;
  float num[8] = {};
  for (int s = 0; s < nsplit; ++s) {
    f32x2 ml = *(const f32x2*)(pml + ((size_t)s * NROWS + row) * 2);
    float w = EXP2(ml.x - M) * ml.y;
    den += w;
    f16x8 o = *(const f16x8*)(pO + ((size_t)s * NROWS + row) * 128 + colg);
    #pragma unroll
    for (int j = 0; j < 8; ++j) num[j] += w * (float)o[j];
  }
  float inv = 1.f / den;
  f32x4 o0, o1;
  #pragma unroll
  for (int j = 0; j < 4; ++j) { o0[j] = num[j] * inv; o1[j] = num[4 + j] * inv; }
  *(f32x4*)(out + (size_t)row * 128 + colg)     = o0;
  *(f32x4*)(out + (size_t)row * 128 + colg + 4) = o1;
}

extern "C" void kernel_launch(void* const* d_in, const int* in_sizes, int n_in,
                              void* d_out, int out_size, void* d_ws, size_t ws_size,
                              hipStream_t stream)
{
  (void)in_sizes; (void)n_in; (void)out_size;
  const float* x  = (const float*)d_in[0];
  const float* Wq = (const float*)d_in[1];
  const float* Wk = (const float*)d_in[2];
  const float* Wv = (const float*)d_in[3];

  char* ws = (char*)d_ws;
  _Float16* qkbuf = (_Float16*)ws;                               // 8.39 MB
  _Float16* vtbuf = (_Float16*)(ws + (size_t)NROWS * 256 * 2);   // 4.19 MB
  const size_t base  = (size_t)NROWS * 256 * 2 + (size_t)4 * 128 * 4096 * 2;
  const size_t perO  = (size_t)NROWS * 128 * 2;                  // 4.19 MB / split (f16)
  const size_t perML = (size_t)NROWS * 2 * 4;                    // 128 KB / split

  int nsplit = 4;
  while (nsplit > 1 && base + (size_t)nsplit * (perO + perML) > ws_size) nsplit >>= 1;

  // Wh (0.79 MB) transient at start of pO region (gemm reads, attn overwrites)
  _Float16* Whb = (_Float16*)(ws + base);
  _Float16* pO  = (_Float16*)(ws + base);
  float*    pml = (float*)(ws + base + (size_t)nsplit * perO);
  float*    out = (float*)d_out;

  cvtw<<<192, 256, 0, stream>>>(Wq, Wk, Wv, Whb);
  dim3 gg(256, 3);
  gemm_qkv<<<gg, 256, 0, stream>>>(x, Whb, qkbuf, vtbuf);
  dim3 ga(S_ / 128, 4, nsplit);
  attn<<<ga, 512, 0, stream>>>(qkbuf, vtbuf, pO, pml, 64 / nsplit);
  combine<<<NROWS / 16, 256, 0, stream>>>(pO, pml, out, nsplit);
}

// Round 16
// 83.327 us; speedup vs baseline: 2.0677x; 1.0059x over previous
//
#include <hip/hip_runtime.h>
#include <stdint.h>

typedef __attribute__((ext_vector_type(8))) _Float16 f16x8;
typedef __attribute__((ext_vector_type(4))) float f32x4;
typedef __attribute__((ext_vector_type(2))) float f32x2;

#define S_ 4096
#define D_ 1024
#define NROWS 16384          // B*S
#define QSCALE 0.045084220f  // (1/sqrt(1024)) * log2(e): Q pre-scale -> exp2 softmax
#define EXP2(x) __builtin_amdgcn_exp2f(x)   // raw v_exp_f32 (2^x)

// ---------------------------------------------------------------------------
// Tiny pre-pass: Wq|Wk|Wv (3 x 128 x 1024 f32 = 1.5 MB) -> concatenated f16.
// ---------------------------------------------------------------------------
__global__ __launch_bounds__(256) void cvtw(
    const float* __restrict__ Wq, const float* __restrict__ Wk,
    const float* __restrict__ Wv, _Float16* __restrict__ Wh)
{
  int i = (blockIdx.x * 256 + threadIdx.x) * 8;
  const float* src = (i < 131072) ? Wq : ((i < 262144) ? Wk : Wv);
  int off = i & 131071;
  f32x4 a = *(const f32x4*)(src + off);
  f32x4 b = *(const f32x4*)(src + off + 4);
  f16x8 h;
  #pragma unroll
  for (int j = 0; j < 4; ++j) { h[j] = (_Float16)a[j]; h[j + 4] = (_Float16)b[j]; }
  *(f16x8*)(Wh + i) = h;
}

// ---------------------------------------------------------------------------
// Projections (r13/r15-proven, unchanged). A staged f32 + cvt-at-fragment;
// B staged f16 (4-bit XOR layout). Q pre-scaled by QSCALE.
// ---------------------------------------------------------------------------
__global__ __launch_bounds__(256) void gemm_qkv(
    const float* __restrict__ x, const _Float16* __restrict__ Wh,
    _Float16* __restrict__ qk, _Float16* __restrict__ vt)
{
  __shared__ char smem[32768];          // A0 0..8K | B0 8..16K | A1 16..24K | B1 24..32K
  char* Ab[2] = { smem,        smem + 16384 };
  char* Bb[2] = { smem + 8192, smem + 24576 };
  const int tid  = threadIdx.x;
  const int lane = tid & 63, wid = tid >> 6;
  const int g = lane >> 4, l15 = lane & 15;
  const int m0 = blockIdx.x * 64;
  const int by = blockIdx.y;

  const char* pA[2];
  #pragma unroll
  for (int it = 0; it < 2; ++it) {
    int G = it * 256 + tid, row = G >> 3, gg = (G & 7) ^ (row & 7);
    pA[it] = (const char*)x + (size_t)(m0 + row) * 4096 + gg * 16;
  }
  const char* pB[2];
  #pragma unroll
  for (int it = 0; it < 2; ++it) {
    int d = it * 256 + tid;
    int rowhi = d >> 4, tt = (d & 15) ^ (rowhi & 15);
    int row = rowhi * 4 + (tt >> 2), gg = tt & 3;
    pB[it] = (const char*)(Wh + (size_t)by * 131072 + (size_t)row * 1024) + gg * 16;
  }

#define GSTAGE(bi) do {                                                        \
    _Pragma("unroll")                                                          \
    for (int it_ = 0; it_ < 2; ++it_) {                                        \
      __builtin_amdgcn_global_load_lds(pA[it_],                                \
          Ab[bi] + it_ * 4096 + wid * 1024, 16, 0, 0);                         \
      pA[it_] += 128;                                                          \
      __builtin_amdgcn_global_load_lds(pB[it_],                                \
          Bb[bi] + it_ * 4096 + wid * 1024, 16, 0, 0);                         \
      pB[it_] += 64;                                                           \
    }                                                                          \
  } while (0)

  f32x4 acc[4][2] = {};

#define GCOMPUTE(bi) do {                                                      \
    f16x8 af[4], bg[2];                                                        \
    _Pragma("unroll")                                                          \
    for (int mt = 0; mt < 4; ++mt) {                                           \
      int row = mt * 16 + l15;                                                 \
      const char* base = Ab[bi] + row * 128;                                   \
      f32x4 a0 = *(const f32x4*)(base + (((2 * g    ) ^ (row & 7)) << 4));     \
      f32x4 a1 = *(const f32x4*)(base + (((2 * g + 1) ^ (row & 7)) << 4));     \
      _Pragma("unroll")                                                        \
      for (int i = 0; i < 4; ++i) {                                            \
        af[mt][i] = (_Float16)a0[i]; af[mt][i + 4] = (_Float16)a1[i];          \
      }                                                                        \
    }                                                                          \
    _Pragma("unroll")                                                          \
    for (int nt = 0; nt < 2; ++nt) {                                           \
      int row = wid * 32 + nt * 16 + l15;                                      \
      int byte = ((row >> 2) * 256) +                                          \
                 (((((row & 3) << 2) | g) ^ ((row >> 2) & 15)) << 4);          \
      bg[nt] = *(const f16x8*)(Bb[bi] + byte);                                 \
    }                                                                          \
    __builtin_amdgcn_s_setprio(1);                                             \
    _Pragma("unroll")                                                          \
    for (int mt = 0; mt < 4; ++mt)                                             \
      _Pragma("unroll")                                                        \
      for (int nt = 0; nt < 2; ++nt)                                           \
        acc[mt][nt] = __builtin_amdgcn_mfma_f32_16x16x32_f16(af[mt], bg[nt],   \
                                                             acc[mt][nt], 0, 0, 0); \
    __builtin_amdgcn_s_setprio(0);                                             \
  } while (0)

  GSTAGE(0);
  __syncthreads();
  for (int t = 0; t < 32; t += 2) {
    GSTAGE(1);
    GCOMPUTE(0);
    __syncthreads();
    if (t + 2 < 32) GSTAGE(0);
    GCOMPUTE(1);
    __syncthreads();
  }

  if (by < 2) {
    const float sc = (by == 0) ? QSCALE : 1.0f;
    #pragma unroll
    for (int mt = 0; mt < 4; ++mt)
      #pragma unroll
      for (int nt = 0; nt < 2; ++nt)
        #pragma unroll
        for (int r = 0; r < 4; ++r) {
          int row = m0 + mt * 16 + (g << 2) + r;
          int col = by * 128 + wid * 32 + nt * 16 + l15;
          qk[(size_t)row * 256 + col] = (_Float16)(acc[mt][nt][r] * sc);
        }
  } else {
    _Float16* T = (_Float16*)smem;
    #pragma unroll
    for (int mt = 0; mt < 4; ++mt)
      #pragma unroll
      for (int nt = 0; nt < 2; ++nt)
        #pragma unroll
        for (int r = 0; r < 4; ++r)
          T[(mt * 16 + (g << 2) + r) * 128 + wid * 32 + nt * 16 + l15] =
              (_Float16)acc[mt][nt][r];
    __syncthreads();
    const int b = m0 >> 12, s_base = m0 & 4095;
    #pragma unroll
    for (int it = 0; it < 4; ++it) {
      int Wn = it * 256 + tid;
      int f = Wn >> 3, gran = Wn & 7;
      int kk = gran >> 2, q = gran & 3;
      f16x8 v;
      #pragma unroll
      for (int i = 0; i < 8; ++i) {
        int h = i >> 2, j = i & 3;
        v[i] = T[(kk * 32 + h * 16 + q * 4 + j) * 128 + f];
      }
      *(f16x8*)((char*)vt + (size_t)(b * 128 + f) * 8192 + s_base * 2 + gran * 16) = v;
    }
  }
#undef GSTAGE
#undef GCOMPUTE
}

// ---------------------------------------------------------------------------
// Flash attention, 32 q-rows/wave (two 16-row groups): each K/V LDS fragment
// is read ONCE and feeds TWO MFMAs -> LDS-read amplification halved (the r15
// bottleneck). 4 waves x 32 q = 128 q/block, 512 blocks = 2/CU. Log2-domain
// softmax with raw v_exp, defer-max THR=8, per-group (m,l) state.
// ---------------------------------------------------------------------------
__global__ __launch_bounds__(256, 2) void attn(const _Float16* __restrict__ qk,
                                               const _Float16* __restrict__ vt,
                                               _Float16* __restrict__ pO,
                                               float* __restrict__ pml,
                                               int ntiles)
{
  __shared__ _Float16 K0l[64 * 128], K1l[64 * 128];
  __shared__ _Float16 V0l[64 * 128], V1l[64 * 128];
  const int tid  = threadIdx.x;
  const int lane = tid & 63, wid = tid >> 6;
  const int g = lane >> 4, l15 = lane & 15;
  const int b  = blockIdx.y;
  const int q0 = blockIdx.x * 128;
  const int split = blockIdx.z;
  const int kv_begin = split * (ntiles * 64);

  f16x8 qf0[4], qf1[4];
  {
    const size_t qr0 = (size_t)(b * S_ + q0 + wid * 32 + l15) * 256;
    #pragma unroll
    for (int kk = 0; kk < 4; ++kk) {
      qf0[kk] = *(const f16x8*)(qk + qr0 + kk * 32 + g * 8);
      qf1[kk] = *(const f16x8*)(qk + qr0 + 16 * 256 + kk * 32 + g * 8);
    }
  }

  // staging: 4 K granules + 4 V granules per thread (256 threads)
  const char* gK[4]; const char* gV[4];
  #pragma unroll
  for (int it = 0; it < 4; ++it) {
    int G = it * 256 + tid;
    int row = G >> 4, ch = G & 15;
    gK[it] = (const char*)qk + (size_t)(b * S_ + kv_begin + row) * 512 + 256 +
             (((ch << 4)) ^ ((row & 15) << 4));
    int f = G >> 3, c = G & 7;
    gV[it] = (const char*)vt + (size_t)(b * 128 + f) * 8192 + (kv_begin >> 6) * 128 +
             ((c ^ (f & 7)) << 4);
  }

#define STAGE(Kb, Vb) do {                                                          \
    _Pragma("unroll")                                                               \
    for (int it_ = 0; it_ < 4; ++it_) {                                             \
      __builtin_amdgcn_global_load_lds(gK[it_],                                     \
          (char*)(Kb) + (it_ * 256 + wid * 64) * 16, 16, 0, 0);                     \
      __builtin_amdgcn_global_load_lds(gV[it_],                                     \
          (char*)(Vb) + (it_ * 256 + wid * 64) * 16, 16, 0, 0);                     \
      gK[it_] += 32768; gV[it_] += 128;                                             \
    }                                                                               \
  } while (0)

  f32x4 oa0[8] = {}, oa1[8] = {};
  float m0r = -1e30f, l0r = 0.f, m1r = -1e30f, l1r = 0.f;

#define COMPUTE(Kb, Vb) do {                                                        \
    f32x4 s0[4] = {}, s1[4] = {};                                                   \
    __builtin_amdgcn_s_setprio(1);                                                  \
    _Pragma("unroll")                                                               \
    for (int kk = 0; kk < 4; ++kk) {                                                \
      const char* kb = (const char*)(Kb) + l15 * 256 +                              \
                       (((kk << 6) | (g << 4)) ^ (l15 << 4));                       \
      _Pragma("unroll")                                                             \
      for (int kvt = 0; kvt < 4; ++kvt) {                                           \
        f16x8 kf = *(const f16x8*)(kb + kvt * 4096);                                \
        s0[kvt] = __builtin_amdgcn_mfma_f32_16x16x32_f16(kf, qf0[kk], s0[kvt],      \
                                                         0, 0, 0);                  \
        s1[kvt] = __builtin_amdgcn_mfma_f32_16x16x32_f16(kf, qf1[kk], s1[kvt],      \
                                                         0, 0, 0);                  \
      }                                                                             \
    }                                                                               \
    __builtin_amdgcn_s_setprio(0);                                                  \
    float p0 = fmaxf(                                                               \
        fmaxf(fmaxf(fmaxf(s0[0][0], s0[0][1]), fmaxf(s0[0][2], s0[0][3])),          \
              fmaxf(fmaxf(s0[1][0], s0[1][1]), fmaxf(s0[1][2], s0[1][3]))),         \
        fmaxf(fmaxf(fmaxf(s0[2][0], s0[2][1]), fmaxf(s0[2][2], s0[2][3])),          \
              fmaxf(fmaxf(s0[3][0], s0[3][1]), fmaxf(s0[3][2], s0[3][3]))));        \
    float p1 = fmaxf(                                                               \
        fmaxf(fmaxf(fmaxf(s1[0][0], s1[0][1]), fmaxf(s1[0][2], s1[0][3])),          \
              fmaxf(fmaxf(s1[1][0], s1[1][1]), fmaxf(s1[1][2], s1[1][3]))),         \
        fmaxf(fmaxf(fmaxf(s1[2][0], s1[2][1]), fmaxf(s1[2][2], s1[2][3])),          \
              fmaxf(fmaxf(s1[3][0], s1[3][1]), fmaxf(s1[3][2], s1[3][3]))));        \
    p0 = fmaxf(p0, __shfl_xor(p0, 16)); p0 = fmaxf(p0, __shfl_xor(p0, 32));         \
    p1 = fmaxf(p1, __shfl_xor(p1, 16)); p1 = fmaxf(p1, __shfl_xor(p1, 32));         \
    if (!__all((p0 - m0r <= 8.0f) && (p1 - m1r <= 8.0f))) {                         \
      float mn0 = fmaxf(m0r, p0), mn1 = fmaxf(m1r, p1);                             \
      float c0 = EXP2(m0r - mn0), c1 = EXP2(m1r - mn1);                             \
      l0r *= c0; m0r = mn0; l1r *= c1; m1r = mn1;                                   \
      _Pragma("unroll")                                                             \
      for (int r = 0; r < 4; ++r) {                                                 \
        int ad = ((g << 2) + r) << 2;                                               \
        float cr0 = __builtin_bit_cast(float,                                       \
            __builtin_amdgcn_ds_bpermute(ad, __builtin_bit_cast(int, c0)));         \
        float cr1 = __builtin_bit_cast(float,                                       \
            __builtin_amdgcn_ds_bpermute(ad, __builtin_bit_cast(int, c1)));         \
        _Pragma("unroll")                                                           \
        for (int ft = 0; ft < 8; ++ft) {                                            \
          oa0[ft][r] *= cr0; oa1[ft][r] *= cr1;                                     \
        }                                                                           \
      }                                                                             \
    }                                                                               \
    float ps0 = 0.f, ps1 = 0.f;                                                     \
    f16x8 pa0[2], pa1[2];                                                           \
    _Pragma("unroll")                                                               \
    for (int k2 = 0; k2 < 2; ++k2)                                                  \
      _Pragma("unroll")                                                             \
      for (int i = 0; i < 8; ++i) {                                                 \
        float e0 = EXP2(s0[2 * k2 + (i >> 2)][i & 3] - m0r);                        \
        float e1 = EXP2(s1[2 * k2 + (i >> 2)][i & 3] - m1r);                        \
        ps0 += e0; ps1 += e1;                                                       \
        pa0[k2][i] = (_Float16)e0; pa1[k2][i] = (_Float16)e1;                       \
      }                                                                             \
    ps0 += __shfl_xor(ps0, 16); ps0 += __shfl_xor(ps0, 32);                         \
    ps1 += __shfl_xor(ps1, 16); ps1 += __shfl_xor(ps1, 32);                         \
    l0r += ps0; l1r += ps1;                                                         \
    __builtin_amdgcn_s_setprio(1);                                                  \
    _Pragma("unroll")                                                               \
    for (int k2 = 0; k2 < 2; ++k2) {                                                \
      const char* vb = (const char*)(Vb) + l15 * 128 +                              \
                       (((k2 << 6) | (g << 4)) ^ ((l15 & 7) << 4));                 \
      _Pragma("unroll")                                                             \
      for (int ft = 0; ft < 8; ++ft) {                                              \
        f16x8 vf = *(const f16x8*)(vb + ft * 2048);                                 \
        oa0[ft] = __builtin_amdgcn_mfma_f32_16x16x32_f16(pa0[k2], vf, oa0[ft],      \
                                                         0, 0, 0);                  \
        oa1[ft] = __builtin_amdgcn_mfma_f32_16x16x32_f16(pa1[k2], vf, oa1[ft],      \
                                                         0, 0, 0);                  \
      }                                                                             \
    }                                                                               \
    __builtin_amdgcn_s_setprio(0);                                                  \
  } while (0)

  STAGE(K0l, V0l);
  __syncthreads();
  for (int t = 0; t < ntiles; t += 2) {
    STAGE(K1l, V1l);
    COMPUTE(K0l, V0l);
    __syncthreads();
    if (t + 2 < ntiles) STAGE(K0l, V0l);
    COMPUTE(K1l, V1l);
    __syncthreads();
  }

  #pragma unroll
  for (int s = 0; s < 2; ++s) {
    float mrun = s ? m1r : m0r, lrun = s ? l1r : l0r;
    f32x4* oa = s ? oa1 : oa0;
    #pragma unroll
    for (int r = 0; r < 4; ++r) {
      int ad = ((g << 2) + r) << 2;
      float mr = __builtin_bit_cast(float,
                   __builtin_amdgcn_ds_bpermute(ad, __builtin_bit_cast(int, mrun)));
      float lr = __builtin_bit_cast(float,
                   __builtin_amdgcn_ds_bpermute(ad, __builtin_bit_cast(int, lrun)));
      float inv = 1.f / lr;
      const int grow = b * S_ + q0 + wid * 32 + s * 16 + (g << 2) + r;
      _Float16* od = pO + ((size_t)split * NROWS + grow) * 128;
      #pragma unroll
      for (int ft = 0; ft < 8; ++ft)
        od[ft * 16 + l15] = (_Float16)(oa[ft][r] * inv);
      if (l15 == 0)
        *(f32x2*)(pml + ((size_t)split * NROWS + grow) * 2) = f32x2{mr, lr};
    }
  }
#undef STAGE
#undef COMPUTE
}

// ---------------------------------------------------------------------------
// Combine (r15-proven, unchanged): 16 rows/block, f16x8 reads, f32x4 writes.
// ---------------------------------------------------------------------------
__global__ __launch_bounds__(256) void combine(const _Float16* __restrict__ pO,
                                               const float* __restrict__ pml,
                                               float* __restrict__ out,
                                               int nsplit)
{
  const int tid  = threadIdx.x;
  const int row  = blockIdx.x * 16 + (tid >> 4);
  const int colg = (tid & 15) * 8;

  float M = -1e30f;
  for (int s = 0; s < nsplit; ++s)
    M = fmaxf(M, pml[((size_t)s * NROWS + row) * 2]);
  float den = 0.f;
  float num[8] = {};
  for (int s = 0; s < nsplit; ++s) {
    f32x2 ml = *(const f32x2*)(pml + ((size_t)s * NROWS + row) * 2);
    float w = EXP2(ml.x - M) * ml.y;
    den += w;
    f16x8 o = *(const f16x8*)(pO + ((size_t)s * NROWS + row) * 128 + colg);
    #pragma unroll
    for (int j = 0; j < 8; ++j) num[j] += w * (float)o[j];
  }
  float inv = 1.f / den;
  f32x4 o0, o1;
  #pragma unroll
  for (int j = 0; j < 4; ++j) { o0[j] = num[j] * inv; o1[j] = num[4 + j] * inv; }
  *(f32x4*)(out + (size_t)row * 128 + colg)     = o0;
  *(f32x4*)(out + (size_t)row * 128 + colg + 4) = o1;
}

extern "C" void kernel_launch(void* const* d_in, const int* in_sizes, int n_in,
                              void* d_out, int out_size, void* d_ws, size_t ws_size,
                              hipStream_t stream)
{
  (void)in_sizes; (void)n_in; (void)out_size;
  const float* x  = (const float*)d_in[0];
  const float* Wq = (const float*)d_in[1];
  const float* Wk = (const float*)d_in[2];
  const float* Wv = (const float*)d_in[3];

  char* ws = (char*)d_ws;
  _Float16* qkbuf = (_Float16*)ws;                               // 8.39 MB
  _Float16* vtbuf = (_Float16*)(ws + (size_t)NROWS * 256 * 2);   // 4.19 MB
  const size_t base  = (size_t)NROWS * 256 * 2 + (size_t)4 * 128 * 4096 * 2;
  const size_t perO  = (size_t)NROWS * 128 * 2;                  // 4.19 MB / split (f16)
  const size_t perML = (size_t)NROWS * 2 * 4;                    // 128 KB / split

  int nsplit = 4;
  while (nsplit > 1 && base + (size_t)nsplit * (perO + perML) > ws_size) nsplit >>= 1;

  // Wh (0.79 MB) transient at start of pO region (gemm reads, attn overwrites)
  _Float16* Whb = (_Float16*)(ws + base);
  _Float16* pO  = (_Float16*)(ws + base);
  float*    pml = (float*)(ws + base + (size_t)nsplit * perO);
  float*    out = (float*)d_out;

  cvtw<<<192, 256, 0, stream>>>(Wq, Wk, Wv, Whb);
  dim3 gg(256, 3);
  gemm_qkv<<<gg, 256, 0, stream>>>(x, Whb, qkbuf, vtbuf);
  dim3 ga(S_ / 128, 4, nsplit);
  attn<<<ga, 256, 0, stream>>>(qkbuf, vtbuf, pO, pml, 64 / nsplit);
  combine<<<NROWS / 16, 256, 0, stream>>>(pO, pml, out, nsplit);
}